// Round 6
// baseline (283.375 us; speedup 1.0000x reference)
//
#include <hip/hip_runtime.h>
#include <cstdint>
#include <cstddef>

// ---- types ----
typedef _Float16 f16x8 __attribute__((ext_vector_type(8)));
typedef _Float16 f16x4 __attribute__((ext_vector_type(4)));
typedef float    f32x4 __attribute__((ext_vector_type(4)));
typedef unsigned short ushort_t;

#define LOG2E 1.4426950408889634f

constexpr int BATCH = 2;
constexpr int TSEQ  = 2048;
constexpr int HID   = 2048;
constexpr int NH    = 16;
constexpr int HD    = 128;
constexpr int GK    = 2048;   // K-dim of both GEMMs
constexpr int NKT   = GK / 64; // 32 K-tiles

__device__ inline f32x4 mfma16(f16x8 a, f16x8 b, f32x4 c) {
    return __builtin_amdgcn_mfma_f32_16x16x32_f16(a, b, c, 0, 0, 0);
}

// async global->LDS, 16B per lane; LDS dest must be linear (base + lane*16)
__device__ inline void async_copy16(const void* src, void* dst_lds) {
    __builtin_amdgcn_global_load_lds(
        (const __attribute__((address_space(1))) uint32_t*)src,
        (__attribute__((address_space(3))) uint32_t*)dst_lds, 16, 0, 0);
}

// ---- fp32 -> fp16 cast, vectorized (G13) ----
__global__ __launch_bounds__(256)
void cast_f32_f16(const float4* __restrict__ in, f16x4* __restrict__ out, int n4) {
    int i = blockIdx.x * 256 + threadIdx.x;
    if (i >= n4) return;
    float4 v = in[i];
    f16x4 o = { (_Float16)v.x, (_Float16)v.y, (_Float16)v.z, (_Float16)v.w };
    out[i] = o;
}

// ---- GEMM v2 (unchanged): 3-ring pipeline, counted vmcnt, T2 swizzle ----
template <int MODE>
__global__ __launch_bounds__(512, 2)
void gemm_bt(const _Float16* __restrict__ A, const _Float16* __restrict__ B,
             float* __restrict__ C, _Float16* __restrict__ Qo,
             _Float16* __restrict__ Ko, _Float16* __restrict__ Vo, int NB) {
    __shared__ __align__(16) _Float16 As[3][256 * 64];
    __shared__ __align__(16) _Float16 Bs[3][128 * 64];

    const int tid  = threadIdx.x;
    const int lane = tid & 63;
    const int w    = tid >> 6;
    const int l15  = lane & 15;
    const int lq   = lane >> 4;
    const int wr   = w >> 1, wc = w & 1;

    const int bid = (int)blockIdx.x;
    const int cpx = (int)gridDim.x >> 3;
    const int swz = (bid & 7) * cpx + (bid >> 3);
    const int bn  = swz % NB, bm = swz / NB;
    const int m0  = bm * 256, n0 = bn * 128;

    const _Float16* Ab = A + (size_t)m0 * GK;
    const _Float16* Bb = B + (size_t)n0 * GK;

    auto stage = [&](int t, int b) {
        const int k0 = t * 64;
        #pragma unroll
        for (int it = 0; it < 4; ++it) {
            const int slot = it * 512 + tid;
            const int row = slot >> 3, c16 = slot & 7;
            const int srcb = c16 ^ (row & 7);
            async_copy16(Ab + (size_t)row * GK + k0 + srcb * 8,
                         (char*)As[b] + slot * 16);
        }
        #pragma unroll
        for (int it = 0; it < 2; ++it) {
            const int slot = it * 512 + tid;
            const int row = slot >> 3, c16 = slot & 7;
            const int srcb = c16 ^ (row & 7);
            async_copy16(Bb + (size_t)row * GK + k0 + srcb * 8,
                         (char*)Bs[b] + slot * 16);
        }
    };

    f32x4 acc[4][4] = {};

    stage(0, 0);
    stage(1, 1);

    for (int t = 0; t < NKT; ++t) {
        if (t + 1 < NKT) asm volatile("s_waitcnt vmcnt(6)" ::: "memory");
        else             asm volatile("s_waitcnt vmcnt(0)" ::: "memory");
        __builtin_amdgcn_s_barrier();
        __builtin_amdgcn_sched_barrier(0);

        const char* At_ = (const char*)As[t % 3];
        const char* Bt_ = (const char*)Bs[t % 3];

        f16x8 af[4][2], bff[4][2];
        #pragma unroll
        for (int i = 0; i < 4; ++i)
            #pragma unroll
            for (int kk = 0; kk < 2; ++kk) {
                const int ra = wr * 64 + i * 16 + l15;
                af[i][kk]  = *(const f16x8*)(At_ + ra * 128 + (((kk * 4 + lq) ^ (ra & 7)) << 4));
                const int rb = wc * 64 + i * 16 + l15;
                bff[i][kk] = *(const f16x8*)(Bt_ + rb * 128 + (((kk * 4 + lq) ^ (rb & 7)) << 4));
            }

        if (t + 2 < NKT) stage(t + 2, (t + 2) % 3);

        __builtin_amdgcn_s_setprio(1);
        #pragma unroll
        for (int kk = 0; kk < 2; ++kk)
            #pragma unroll
            for (int i = 0; i < 4; ++i)
                #pragma unroll
                for (int j = 0; j < 4; ++j)
                    acc[i][j] = mfma16(af[i][kk], bff[j][kk], acc[i][j]);
        __builtin_amdgcn_s_setprio(0);
    }

    if (MODE == 0) {
        #pragma unroll
        for (int j = 0; j < 4; ++j) {
            const int ncol = n0 + wc * 64 + j * 16 + l15;
            const int which = ncol >> 11;
            const int oo = ncol & 2047;
            const int head = oo >> 7;
            const int d = oo & 127;
            _Float16* dst = (which == 0) ? Qo : (which == 1) ? Ko : Vo;
            const float scl = (which == 0) ? 0.08838834764831845f : 1.0f;
            #pragma unroll
            for (int i = 0; i < 4; ++i) {
                #pragma unroll
                for (int r = 0; r < 4; ++r) {
                    const int m = m0 + wr * 64 + i * 16 + lq * 4 + r;
                    const int b = m >> 11, tt = m & 2047;
                    dst[((size_t)(b * NH + head) * TSEQ + tt) * HD + d] =
                        (_Float16)(acc[i][j][r] * scl);
                }
            }
        }
    } else {
        #pragma unroll
        for (int i = 0; i < 4; ++i)
            #pragma unroll
            for (int j = 0; j < 4; ++j)
                #pragma unroll
                for (int r = 0; r < 4; ++r) {
                    const int m = m0 + wr * 64 + i * 16 + lq * 4 + r;
                    const int n = n0 + wc * 64 + j * 16 + l15;
                    C[(size_t)m * HID + n] = acc[i][j][r];
                }
    }
}

// ---- causal flash attention v5 ----
// 512 blocks x 4 waves, QBLK=128 (32 q-rows/wave: 2 q-frags, K/V frags reg-reused
// across them -> 2x MFMA per LDS read). 80KB LDS -> 2 blocks/CU. Heavy-first.
__global__ __launch_bounds__(256, 2)
void attn_fwd(const _Float16* __restrict__ Q, const _Float16* __restrict__ K,
              const _Float16* __restrict__ V, _Float16* __restrict__ O) {
    __shared__ __align__(16) char Ks[2][64 * 256];   // [64][128] f16, swizzled (32KB)
    __shared__ __align__(16) char Vt[2][128 * 128];  // [128][64] f16 V^T, swizzled (32KB)
    __shared__ __align__(16) char Ps[4][4096];       // per-wave [32][64] f16 P (16KB)

    const int tid  = threadIdx.x;
    const int lane = tid & 63;
    const int w    = tid >> 6;      // 0..3
    const int l15  = lane & 15;
    const int lq   = lane >> 4;

    const int qt = 15 - ((int)blockIdx.x >> 5);   // heavy q-tiles dispatched first
    const int bh = (int)blockIdx.x & 31;
    const int b = bh >> 4, h = bh & 15;

    const size_t base = (size_t)bh * TSEQ * HD;
    const _Float16* Qp = Q + base;
    const _Float16* Kp = K + base;
    const _Float16* Vp = V + base;

    const int q0 = qt * 128;
    const int NT = 2 * qt + 2;
    const int qw = q0 + w * 32;     // this wave's first q-row

    const f16x8 ones = { (_Float16)1.f, (_Float16)1.f, (_Float16)1.f, (_Float16)1.f,
                         (_Float16)1.f, (_Float16)1.f, (_Float16)1.f, (_Float16)1.f };

    // Q hoisted: 2 q-frag groups x 4 k-slices
    f16x8 qf[2][4];
    #pragma unroll
    for (int qh = 0; qh < 2; ++qh)
        #pragma unroll
        for (int ks = 0; ks < 4; ++ks)
            qf[qh][ks] = *(const f16x8*)(Qp + (size_t)(qw + qh * 16 + l15) * HD + ks * 32 + lq * 8);

    f32x4 o[8][2] = {};
    f32x4 osum[2] = {};
    float m_run[2][4];
    #pragma unroll
    for (int qh = 0; qh < 2; ++qh)
        #pragma unroll
        for (int r = 0; r < 4; ++r) m_run[qh][r] = -1e30f;

    uint4 vv[4];
    auto loadV = [&](int t) {   // lane = kv row; wave w owns d-chunks w*4..w*4+3
        const int row = tid & 63;
        #pragma unroll
        for (int it = 0; it < 4; ++it) {
            const int c8 = w * 4 + it;
            vv[it] = *(const uint4*)(Vp + (size_t)(t * 64 + row) * HD + c8 * 8);
        }
    };
    auto stageK = [&](int t, int buf) {
        #pragma unroll
        for (int it = 0; it < 4; ++it) {
            const int slot = it * 256 + tid;
            const int row = slot >> 4, c16 = slot & 15;
            const int srcb = c16 ^ (row & 7);
            async_copy16(Kp + (size_t)(t * 64 + row) * HD + srcb * 8, Ks[buf] + slot * 16);
        }
    };
    auto writeV = [&](int buf) {   // ushort stores at d*128 + row*2: 2-way, free
        const int row = tid & 63;
        #pragma unroll
        for (int it = 0; it < 4; ++it) {
            const int c8 = w * 4 + it;
            const uint32_t wrd[4] = {vv[it].x, vv[it].y, vv[it].z, vv[it].w};
            #pragma unroll
            for (int p2 = 0; p2 < 4; ++p2) {
                const int d0 = c8 * 8 + p2 * 2, d1 = d0 + 1;
                int b0 = d0 * 128 + row * 2; b0 ^= (d0 & 7) << 4;
                int b1 = d1 * 128 + row * 2; b1 ^= (d1 & 7) << 4;
                *(ushort_t*)(Vt[buf] + b0) = (ushort_t)(wrd[p2] & 0xffffu);
                *(ushort_t*)(Vt[buf] + b1) = (ushort_t)(wrd[p2] >> 16);
            }
        }
    };

    char* Pb = Ps[w];

    loadV(0);
    stageK(0, 0);

    int cur = 0;
    for (int t = 0; t < NT; ++t) {
        writeV(cur);
        __syncthreads();
        if (t + 1 < NT) {
            loadV(t + 1);
            stageK(t + 1, cur ^ 1);
        }

        const int kv0 = t * 64;
        if (kv0 <= qw + 31) {       // wave-uniform skip of fully-masked tiles
            // S = Q K^T ; each K-frag feeds both q-frag groups (reg reuse)
            f32x4 s[2][4] = {};
            __builtin_amdgcn_s_setprio(1);
            #pragma unroll
            for (int ks = 0; ks < 4; ++ks) {
                #pragma unroll
                for (int nf = 0; nf < 4; ++nf) {
                    const int r   = nf * 16 + l15;
                    const int blk = (ks * 4 + lq) ^ (r & 7);
                    const f16x8 kf = *(const f16x8*)(Ks[cur] + r * 256 + blk * 16);
                    s[0][nf] = mfma16(qf[0][ks], kf, s[0][nf]);
                    s[1][nf] = mfma16(qf[1][ks], kf, s[1][nf]);
                }
            }
            __builtin_amdgcn_s_setprio(0);

            if (kv0 + 63 > qw) {    // diagonal-crossing for this wave
                #pragma unroll
                for (int qh = 0; qh < 2; ++qh)
                    #pragma unroll
                    for (int nf = 0; nf < 4; ++nf) {
                        const int kvp = kv0 + nf * 16 + l15;
                        #pragma unroll
                        for (int r = 0; r < 4; ++r)
                            if (kvp > qw + qh * 16 + lq * 4 + r) s[qh][nf][r] = -1e30f;
                    }
            }

            // lazy max: local check only; full shuffle-reduce when triggered
            float lmax[2][4];
            bool need = false;
            #pragma unroll
            for (int qh = 0; qh < 2; ++qh)
                #pragma unroll
                for (int r = 0; r < 4; ++r) {
                    const float v = fmaxf(fmaxf(s[qh][0][r], s[qh][1][r]),
                                          fmaxf(s[qh][2][r], s[qh][3][r]));
                    lmax[qh][r] = v;
                    need = need || (v > m_run[qh][r] + 5.0f);
                }
            if (__any(need)) {
                float alpha[2][4];
                #pragma unroll
                for (int qh = 0; qh < 2; ++qh)
                    #pragma unroll
                    for (int r = 0; r < 4; ++r) {
                        float v = lmax[qh][r];
                        v = fmaxf(v, __shfl_xor(v, 1));
                        v = fmaxf(v, __shfl_xor(v, 2));
                        v = fmaxf(v, __shfl_xor(v, 4));
                        v = fmaxf(v, __shfl_xor(v, 8));
                        const float mn = fmaxf(m_run[qh][r], v);
                        alpha[qh][r] = __builtin_exp2f((m_run[qh][r] - mn) * LOG2E);
                        m_run[qh][r] = mn;
                    }
                #pragma unroll
                for (int df = 0; df < 8; ++df)
                    #pragma unroll
                    for (int qh = 0; qh < 2; ++qh)
                        #pragma unroll
                        for (int r = 0; r < 4; ++r)
                            o[df][qh][r] *= alpha[qh][r];
                #pragma unroll
                for (int qh = 0; qh < 2; ++qh)
                    #pragma unroll
                    for (int r = 0; r < 4; ++r)
                        osum[qh][r] *= alpha[qh][r];
            }

            // P = exp(S - m) -> wave-private LDS (f16), rows qp = qh*16+lq*4+r
            #pragma unroll
            for (int qh = 0; qh < 2; ++qh)
                #pragma unroll
                for (int nf = 0; nf < 4; ++nf)
                    #pragma unroll
                    for (int r = 0; r < 4; ++r) {
                        const float p = __builtin_exp2f((s[qh][nf][r] - m_run[qh][r]) * LOG2E);
                        const int qp = qh * 16 + lq * 4 + r;
                        int byt = qp * 128 + (nf * 16 + l15) * 2;
                        byt ^= (qp & 7) << 4;
                        union { _Float16 hf; ushort_t u; } cv;
                        cv.hf = (_Float16)p;
                        *(ushort_t*)(Pb + byt) = cv.u;  // wave-private, in-order LDS
                    }

            // O += P @ V ; osum += P @ 1 ; V-frags reg-reused across q-frag groups
            __builtin_amdgcn_s_setprio(1);
            #pragma unroll
            for (int ks2 = 0; ks2 < 2; ++ks2) {
                const int pblk = (ks2 * 4 + lq) ^ (l15 & 7);
                const f16x8 pf0 = *(const f16x8*)(Pb + l15 * 128 + pblk * 16);
                const f16x8 pf1 = *(const f16x8*)(Pb + (16 + l15) * 128 + pblk * 16);
                #pragma unroll
                for (int df = 0; df < 8; ++df) {
                    const int vr   = df * 16 + l15;
                    const int vblk = (ks2 * 4 + lq) ^ (vr & 7);
                    const f16x8 vf = *(const f16x8*)(Vt[cur] + vr * 128 + vblk * 16);
                    o[df][0] = mfma16(pf0, vf, o[df][0]);
                    o[df][1] = mfma16(pf1, vf, o[df][1]);
                }
                osum[0] = mfma16(pf0, ones, osum[0]);
                osum[1] = mfma16(pf1, ones, osum[1]);
            }
            __builtin_amdgcn_s_setprio(0);
        }
        cur ^= 1;
    }

    float rl[2][4];
    #pragma unroll
    for (int qh = 0; qh < 2; ++qh)
        #pragma unroll
        for (int r = 0; r < 4; ++r) rl[qh][r] = 1.0f / osum[qh][r];
    #pragma unroll
    for (int df = 0; df < 8; ++df)
        #pragma unroll
        for (int qh = 0; qh < 2; ++qh)
            #pragma unroll
            for (int r = 0; r < 4; ++r) {
                const int qg = qw + qh * 16 + lq * 4 + r;
                const int dg = df * 16 + l15;
                O[((size_t)(b * TSEQ + qg)) * HID + h * HD + dg] =
                    (_Float16)(o[df][qh][r] * rl[qh][r]);
            }
}

extern "C" void kernel_launch(void* const* d_in, const int* in_sizes, int n_in,
                              void* d_out, int out_size, void* d_ws, size_t ws_size,
                              hipStream_t stream) {
    (void)in_sizes; (void)n_in; (void)out_size; (void)ws_size;
    const float* hs   = (const float*)d_in[0];
    const float* wqkv = (const float*)d_in[1];
    const float* wout = (const float*)d_in[2];

    char* ws = (char*)d_ws;
    size_t off = 0;
    _Float16* hs_h   = (_Float16*)(ws + off); off += (size_t)BATCH * TSEQ * HID * 2;
    _Float16* wqkv_h = (_Float16*)(ws + off); off += (size_t)3 * HID * HID * 2;
    _Float16* wout_h = (_Float16*)(ws + off); off += (size_t)HID * HID * 2;
    _Float16* Qh     = (_Float16*)(ws + off); off += (size_t)BATCH * NH * TSEQ * HD * 2;
    _Float16* Kh     = (_Float16*)(ws + off); off += (size_t)BATCH * NH * TSEQ * HD * 2;
    _Float16* Vh     = (_Float16*)(ws + off); off += (size_t)BATCH * NH * TSEQ * HD * 2;
    _Float16* At     = (_Float16*)(ws + off); off += (size_t)BATCH * TSEQ * HID * 2;

    const int n4_hs   = BATCH * TSEQ * HID / 4;
    const int n4_wqkv = 3 * HID * HID / 4;
    const int n4_wout = HID * HID / 4;
    cast_f32_f16<<<dim3((n4_hs   + 255) / 256), dim3(256), 0, stream>>>((const float4*)hs,   (f16x4*)hs_h,   n4_hs);
    cast_f32_f16<<<dim3((n4_wqkv + 255) / 256), dim3(256), 0, stream>>>((const float4*)wqkv, (f16x4*)wqkv_h, n4_wqkv);
    cast_f32_f16<<<dim3((n4_wout + 255) / 256), dim3(256), 0, stream>>>((const float4*)wout, (f16x4*)wout_h, n4_wout);

    gemm_bt<0><<<dim3(768), dim3(512), 0, stream>>>(
        hs_h, wqkv_h, nullptr, Qh, Kh, Vh, 48);

    attn_fwd<<<dim3(512), dim3(256), 0, stream>>>(Qh, Kh, Vh, At);

    gemm_bt<1><<<dim3(256), dim3(512), 0, stream>>>(
        At, wout_h, (float*)d_out, nullptr, nullptr, nullptr, 16);
}

// Round 7
// 267.017 us; speedup vs baseline: 1.0613x; 1.0613x over previous
//
#include <hip/hip_runtime.h>
#include <cstdint>
#include <cstddef>

// ---- types ----
typedef _Float16 f16x8 __attribute__((ext_vector_type(8)));
typedef _Float16 f16x4 __attribute__((ext_vector_type(4)));
typedef float    f32x4 __attribute__((ext_vector_type(4)));
typedef unsigned short ushort_t;

#define LOG2E 1.4426950408889634f

constexpr int BATCH = 2;
constexpr int TSEQ  = 2048;
constexpr int HID   = 2048;
constexpr int NH    = 16;
constexpr int HD    = 128;
constexpr int GK    = 2048;   // K-dim of both GEMMs
constexpr int NKT   = GK / 64; // 32 K-tiles

__device__ inline f32x4 mfma16(f16x8 a, f16x8 b, f32x4 c) {
    return __builtin_amdgcn_mfma_f32_16x16x32_f16(a, b, c, 0, 0, 0);
}

// async global->LDS, 16B per lane; LDS dest must be linear (base + lane*16)
__device__ inline void async_copy16(const void* src, void* dst_lds) {
    __builtin_amdgcn_global_load_lds(
        (const __attribute__((address_space(1))) uint32_t*)src,
        (__attribute__((address_space(3))) uint32_t*)dst_lds, 16, 0, 0);
}

// ---- fp32 -> fp16 cast, vectorized (G13) ----
__global__ __launch_bounds__(256)
void cast_f32_f16(const float4* __restrict__ in, f16x4* __restrict__ out, int n4) {
    int i = blockIdx.x * 256 + threadIdx.x;
    if (i >= n4) return;
    float4 v = in[i];
    f16x4 o = { (_Float16)v.x, (_Float16)v.y, (_Float16)v.z, (_Float16)v.w };
    out[i] = o;
}

// ---- GEMM v2 (unchanged): 3-ring pipeline, counted vmcnt, T2 swizzle ----
template <int MODE>
__global__ __launch_bounds__(512, 2)
void gemm_bt(const _Float16* __restrict__ A, const _Float16* __restrict__ B,
             float* __restrict__ C, _Float16* __restrict__ Qo,
             _Float16* __restrict__ Ko, _Float16* __restrict__ Vo, int NB) {
    __shared__ __align__(16) _Float16 As[3][256 * 64];
    __shared__ __align__(16) _Float16 Bs[3][128 * 64];

    const int tid  = threadIdx.x;
    const int lane = tid & 63;
    const int w    = tid >> 6;
    const int l15  = lane & 15;
    const int lq   = lane >> 4;
    const int wr   = w >> 1, wc = w & 1;

    const int bid = (int)blockIdx.x;
    const int cpx = (int)gridDim.x >> 3;
    const int swz = (bid & 7) * cpx + (bid >> 3);
    const int bn  = swz % NB, bm = swz / NB;
    const int m0  = bm * 256, n0 = bn * 128;

    const _Float16* Ab = A + (size_t)m0 * GK;
    const _Float16* Bb = B + (size_t)n0 * GK;

    auto stage = [&](int t, int b) {
        const int k0 = t * 64;
        #pragma unroll
        for (int it = 0; it < 4; ++it) {
            const int slot = it * 512 + tid;
            const int row = slot >> 3, c16 = slot & 7;
            const int srcb = c16 ^ (row & 7);
            async_copy16(Ab + (size_t)row * GK + k0 + srcb * 8,
                         (char*)As[b] + slot * 16);
        }
        #pragma unroll
        for (int it = 0; it < 2; ++it) {
            const int slot = it * 512 + tid;
            const int row = slot >> 3, c16 = slot & 7;
            const int srcb = c16 ^ (row & 7);
            async_copy16(Bb + (size_t)row * GK + k0 + srcb * 8,
                         (char*)Bs[b] + slot * 16);
        }
    };

    f32x4 acc[4][4] = {};

    stage(0, 0);
    stage(1, 1);

    for (int t = 0; t < NKT; ++t) {
        if (t + 1 < NKT) asm volatile("s_waitcnt vmcnt(6)" ::: "memory");
        else             asm volatile("s_waitcnt vmcnt(0)" ::: "memory");
        __builtin_amdgcn_s_barrier();
        __builtin_amdgcn_sched_barrier(0);

        const char* At_ = (const char*)As[t % 3];
        const char* Bt_ = (const char*)Bs[t % 3];

        f16x8 af[4][2], bff[4][2];
        #pragma unroll
        for (int i = 0; i < 4; ++i)
            #pragma unroll
            for (int kk = 0; kk < 2; ++kk) {
                const int ra = wr * 64 + i * 16 + l15;
                af[i][kk]  = *(const f16x8*)(At_ + ra * 128 + (((kk * 4 + lq) ^ (ra & 7)) << 4));
                const int rb = wc * 64 + i * 16 + l15;
                bff[i][kk] = *(const f16x8*)(Bt_ + rb * 128 + (((kk * 4 + lq) ^ (rb & 7)) << 4));
            }

        if (t + 2 < NKT) stage(t + 2, (t + 2) % 3);

        __builtin_amdgcn_s_setprio(1);
        #pragma unroll
        for (int kk = 0; kk < 2; ++kk)
            #pragma unroll
            for (int i = 0; i < 4; ++i)
                #pragma unroll
                for (int j = 0; j < 4; ++j)
                    acc[i][j] = mfma16(af[i][kk], bff[j][kk], acc[i][j]);
        __builtin_amdgcn_s_setprio(0);
    }

    if (MODE == 0) {
        #pragma unroll
        for (int j = 0; j < 4; ++j) {
            const int ncol = n0 + wc * 64 + j * 16 + l15;
            const int which = ncol >> 11;
            const int oo = ncol & 2047;
            const int head = oo >> 7;
            const int d = oo & 127;
            _Float16* dst = (which == 0) ? Qo : (which == 1) ? Ko : Vo;
            const float scl = (which == 0) ? 0.08838834764831845f : 1.0f;
            #pragma unroll
            for (int i = 0; i < 4; ++i) {
                #pragma unroll
                for (int r = 0; r < 4; ++r) {
                    const int m = m0 + wr * 64 + i * 16 + lq * 4 + r;
                    const int b = m >> 11, tt = m & 2047;
                    dst[((size_t)(b * NH + head) * TSEQ + tt) * HD + d] =
                        (_Float16)(acc[i][j][r] * scl);
                }
            }
        }
    } else {
        #pragma unroll
        for (int i = 0; i < 4; ++i)
            #pragma unroll
            for (int j = 0; j < 4; ++j)
                #pragma unroll
                for (int r = 0; r < 4; ++r) {
                    const int m = m0 + wr * 64 + i * 16 + lq * 4 + r;
                    const int n = n0 + wc * 64 + j * 16 + l15;
                    C[(size_t)m * HID + n] = acc[i][j][r];
                }
    }
}

// ---- causal flash attention v6 ----
// v4 structure (QBLK=64, 4 waves x 16 rows, triangle pairs -> 512 uniform blocks,
// ones-MFMA sum, lazy max) with SINGLE-buffered Ks/Vt: 40KB LDS -> 4 blocks/CU
// (16 waves, 50% occupancy cap). 2 barriers/tile; register V-prefetch hides HBM.
__global__ __launch_bounds__(256)
void attn_fwd(const _Float16* __restrict__ Q, const _Float16* __restrict__ K,
              const _Float16* __restrict__ V, _Float16* __restrict__ O) {
    __shared__ __align__(16) char Ks[64 * 256];   // [64][128] f16, swizzled (16KB)
    __shared__ __align__(16) char Vt[128 * 128];  // [128][64] f16 V^T, swizzled (16KB)
    __shared__ __align__(16) char Ps[4][2048];    // per-wave [16][64] f16 P (8KB)

    const int tid  = threadIdx.x;
    const int lane = tid & 63;
    const int w    = tid >> 6;      // 0..3
    const int l15  = lane & 15;
    const int lq   = lane >> 4;

    const int bh   = (int)blockIdx.x & 31;   // same-bh blocks share XCD (bid&7=bh&7)
    const int pair = (int)blockIdx.x >> 5;   // 0..15
    const int b = bh >> 4, h = bh & 15;

    const size_t base = (size_t)bh * TSEQ * HD;
    const _Float16* Qp = Q + base;
    const _Float16* Kp = K + base;
    const _Float16* Vp = V + base;

    const f16x8 ones = { (_Float16)1.f, (_Float16)1.f, (_Float16)1.f, (_Float16)1.f,
                         (_Float16)1.f, (_Float16)1.f, (_Float16)1.f, (_Float16)1.f };

    uint4 vv[4];
    auto loadV = [&](int t) {   // lane = kv row; wave w owns d-chunks w*4..w*4+3
        const int row = tid & 63;
        #pragma unroll
        for (int it = 0; it < 4; ++it) {
            const int c8 = w * 4 + it;
            vv[it] = *(const uint4*)(Vp + (size_t)(t * 64 + row) * HD + c8 * 8);
        }
    };
    auto stageK = [&](int t) {
        #pragma unroll
        for (int it = 0; it < 4; ++it) {
            const int slot = it * 256 + tid;
            const int row = slot >> 4, c16 = slot & 15;
            const int srcb = c16 ^ (row & 7);
            async_copy16(Kp + (size_t)(t * 64 + row) * HD + srcb * 8, Ks + slot * 16);
        }
    };
    auto writeV = [&]() {   // ushort stores at d*128 + row*2: 2-way, free
        const int row = tid & 63;
        #pragma unroll
        for (int it = 0; it < 4; ++it) {
            const int c8 = w * 4 + it;
            const uint32_t wrd[4] = {vv[it].x, vv[it].y, vv[it].z, vv[it].w};
            #pragma unroll
            for (int p2 = 0; p2 < 4; ++p2) {
                const int d0 = c8 * 8 + p2 * 2, d1 = d0 + 1;
                int b0 = d0 * 128 + row * 2; b0 ^= (d0 & 7) << 4;
                int b1 = d1 * 128 + row * 2; b1 ^= (d1 & 7) << 4;
                *(ushort_t*)(Vt + b0) = (ushort_t)(wrd[p2] & 0xffffu);
                *(ushort_t*)(Vt + b1) = (ushort_t)(wrd[p2] >> 16);
            }
        }
    };

    char* Pb = Ps[w];

    for (int phase = 0; phase < 2; ++phase) {
        const int qt = phase ? pair : (31 - pair);
        const int q0 = qt * 64;
        const int NT = qt + 1;

        if (phase) __syncthreads();   // all waves done with phase-0 LDS before reuse

        const int qrow = q0 + w * 16 + l15;
        f16x8 qf[4];
        #pragma unroll
        for (int ks = 0; ks < 4; ++ks)
            qf[ks] = *(const f16x8*)(Qp + (size_t)qrow * HD + ks * 32 + lq * 8);

        f32x4 o[8] = {};
        f32x4 osum = {};
        float m_run[4];
        #pragma unroll
        for (int r = 0; r < 4; ++r) m_run[r] = -1e30f;

        stageK(0);      // async into Ks (safe: phase barrier / fresh start)
        loadV(0);       // register prefetch

        for (int t = 0; t < NT; ++t) {
            writeV();             // vv(t) -> Vt (readers of t-1 drained at barrier A)
            __syncthreads();      // barrier B: stageK(t) drained (vmcnt0) + writeV visible
            if (t + 1 < NT) loadV(t + 1);   // register prefetch under compute

            const int kv0 = t * 64;
            // S = Q K^T
            f32x4 s[4] = {};
            __builtin_amdgcn_s_setprio(1);
            #pragma unroll
            for (int ks = 0; ks < 4; ++ks) {
                #pragma unroll
                for (int nf = 0; nf < 4; ++nf) {
                    const int r   = nf * 16 + l15;
                    const int blk = (ks * 4 + lq) ^ (r & 7);
                    const f16x8 kf = *(const f16x8*)(Ks + r * 256 + blk * 16);
                    s[nf] = mfma16(qf[ks], kf, s[nf]);
                }
            }
            __builtin_amdgcn_s_setprio(0);

            if (kv0 + 63 > q0 + w * 16) {   // diagonal-crossing for this wave
                #pragma unroll
                for (int nf = 0; nf < 4; ++nf) {
                    const int kvp = kv0 + nf * 16 + l15;
                    #pragma unroll
                    for (int r = 0; r < 4; ++r)
                        if (kvp > q0 + w * 16 + lq * 4 + r) s[nf][r] = -1e30f;
                }
            }

            // lazy max: local check; full shuffle-reduce only when triggered
            bool need = false;
            #pragma unroll
            for (int r = 0; r < 4; ++r) {
                const float v = fmaxf(fmaxf(s[0][r], s[1][r]), fmaxf(s[2][r], s[3][r]));
                need = need || (v > m_run[r] + 5.0f);
            }
            if (__any(need)) {
                float alpha[4];
                #pragma unroll
                for (int r = 0; r < 4; ++r) {
                    float v = fmaxf(fmaxf(s[0][r], s[1][r]), fmaxf(s[2][r], s[3][r]));
                    v = fmaxf(v, __shfl_xor(v, 1));
                    v = fmaxf(v, __shfl_xor(v, 2));
                    v = fmaxf(v, __shfl_xor(v, 4));
                    v = fmaxf(v, __shfl_xor(v, 8));
                    const float mn = fmaxf(m_run[r], v);
                    alpha[r] = __builtin_exp2f((m_run[r] - mn) * LOG2E);
                    m_run[r] = mn;
                }
                #pragma unroll
                for (int df = 0; df < 8; ++df)
                    #pragma unroll
                    for (int r = 0; r < 4; ++r)
                        o[df][r] *= alpha[r];
                #pragma unroll
                for (int r = 0; r < 4; ++r) osum[r] *= alpha[r];
            }

            // P = exp(S - m) -> wave-private LDS (f16)
            #pragma unroll
            for (int nf = 0; nf < 4; ++nf) {
                #pragma unroll
                for (int r = 0; r < 4; ++r) {
                    const float p = __builtin_exp2f((s[nf][r] - m_run[r]) * LOG2E);
                    const int qp = lq * 4 + r;
                    int byt = qp * 128 + (nf * 16 + l15) * 2;
                    byt ^= (qp & 7) << 4;
                    union { _Float16 hf; ushort_t u; } cv;
                    cv.hf = (_Float16)p;
                    *(ushort_t*)(Pb + byt) = cv.u;   // wave-private, in-order LDS
                }
            }

            // O += P @ V ; osum += P @ 1
            __builtin_amdgcn_s_setprio(1);
            #pragma unroll
            for (int ks2 = 0; ks2 < 2; ++ks2) {
                const int pblk = (ks2 * 4 + lq) ^ (l15 & 7);
                const f16x8 pf = *(const f16x8*)(Pb + l15 * 128 + pblk * 16);
                #pragma unroll
                for (int df = 0; df < 8; ++df) {
                    const int vr   = df * 16 + l15;
                    const int vblk = (ks2 * 4 + lq) ^ (vr & 7);
                    const f16x8 vf = *(const f16x8*)(Vt + vr * 128 + vblk * 16);
                    o[df] = mfma16(pf, vf, o[df]);
                }
                osum = mfma16(pf, ones, osum);
            }
            __builtin_amdgcn_s_setprio(0);

            if (t + 1 < NT) {
                __syncthreads();     // barrier A: all waves done reading Ks/Vt(t)
                stageK(t + 1);       // async overwrite of Ks; drains at next barrier B
            }
        }

        float rl[4];
        #pragma unroll
        for (int r = 0; r < 4; ++r) rl[r] = 1.0f / osum[r];
        #pragma unroll
        for (int df = 0; df < 8; ++df) {
            #pragma unroll
            for (int r = 0; r < 4; ++r) {
                const int qg = q0 + w * 16 + lq * 4 + r;
                const int dg = df * 16 + l15;
                O[((size_t)(b * TSEQ + qg)) * HID + h * HD + dg] =
                    (_Float16)(o[df][r] * rl[r]);
            }
        }
    }
}

extern "C" void kernel_launch(void* const* d_in, const int* in_sizes, int n_in,
                              void* d_out, int out_size, void* d_ws, size_t ws_size,
                              hipStream_t stream) {
    (void)in_sizes; (void)n_in; (void)out_size; (void)ws_size;
    const float* hs   = (const float*)d_in[0];
    const float* wqkv = (const float*)d_in[1];
    const float* wout = (const float*)d_in[2];

    char* ws = (char*)d_ws;
    size_t off = 0;
    _Float16* hs_h   = (_Float16*)(ws + off); off += (size_t)BATCH * TSEQ * HID * 2;
    _Float16* wqkv_h = (_Float16*)(ws + off); off += (size_t)3 * HID * HID * 2;
    _Float16* wout_h = (_Float16*)(ws + off); off += (size_t)HID * HID * 2;
    _Float16* Qh     = (_Float16*)(ws + off); off += (size_t)BATCH * NH * TSEQ * HD * 2;
    _Float16* Kh     = (_Float16*)(ws + off); off += (size_t)BATCH * NH * TSEQ * HD * 2;
    _Float16* Vh     = (_Float16*)(ws + off); off += (size_t)BATCH * NH * TSEQ * HD * 2;
    _Float16* At     = (_Float16*)(ws + off); off += (size_t)BATCH * TSEQ * HID * 2;

    const int n4_hs   = BATCH * TSEQ * HID / 4;
    const int n4_wqkv = 3 * HID * HID / 4;
    const int n4_wout = HID * HID / 4;
    cast_f32_f16<<<dim3((n4_hs   + 255) / 256), dim3(256), 0, stream>>>((const float4*)hs,   (f16x4*)hs_h,   n4_hs);
    cast_f32_f16<<<dim3((n4_wqkv + 255) / 256), dim3(256), 0, stream>>>((const float4*)wqkv, (f16x4*)wqkv_h, n4_wqkv);
    cast_f32_f16<<<dim3((n4_wout + 255) / 256), dim3(256), 0, stream>>>((const float4*)wout, (f16x4*)wout_h, n4_wout);

    gemm_bt<0><<<dim3(768), dim3(512), 0, stream>>>(
        hs_h, wqkv_h, nullptr, Qh, Kh, Vh, 48);

    attn_fwd<<<dim3(512), dim3(256), 0, stream>>>(Qh, Kh, Vh, At);

    gemm_bt<1><<<dim3(256), dim3(512), 0, stream>>>(
        At, wout_h, (float*)d_out, nullptr, nullptr, nullptr, 16);
}

// Round 8
// 265.794 us; speedup vs baseline: 1.0661x; 1.0046x over previous
//
#include <hip/hip_runtime.h>
#include <cstdint>
#include <cstddef>

// ---- types ----
typedef _Float16 f16x8 __attribute__((ext_vector_type(8)));
typedef _Float16 f16x4 __attribute__((ext_vector_type(4)));
typedef float    f32x4 __attribute__((ext_vector_type(4)));
typedef unsigned short ushort_t;

#define LOG2E 1.4426950408889634f

constexpr int BATCH = 2;
constexpr int TSEQ  = 2048;
constexpr int HID   = 2048;
constexpr int NH    = 16;
constexpr int HD    = 128;
constexpr int GK    = 2048;   // K-dim of both GEMMs
constexpr int NKT   = GK / 64; // 32 K-tiles

__device__ inline f32x4 mfma16(f16x8 a, f16x8 b, f32x4 c) {
    return __builtin_amdgcn_mfma_f32_16x16x32_f16(a, b, c, 0, 0, 0);
}

// async global->LDS, 16B per lane; LDS dest must be linear (base + lane*16)
__device__ inline void async_copy16(const void* src, void* dst_lds) {
    __builtin_amdgcn_global_load_lds(
        (const __attribute__((address_space(1))) uint32_t*)src,
        (__attribute__((address_space(3))) uint32_t*)dst_lds, 16, 0, 0);
}

// ---- fp32 -> fp16 cast, all three tensors in one launch ----
__global__ __launch_bounds__(256)
void cast_all(const float4* __restrict__ hs, const float4* __restrict__ wqkv,
              const float4* __restrict__ wout, f16x4* __restrict__ hs_h,
              f16x4* __restrict__ wqkv_h, f16x4* __restrict__ wout_h,
              int n_hs, int n_wqkv, int n_wout) {
    int i = blockIdx.x * 256 + threadIdx.x;
    const float4* src; f16x4* dst; int j;
    if (i < n_hs)                 { src = hs;   dst = hs_h;   j = i; }
    else if (i < n_hs + n_wqkv)   { src = wqkv; dst = wqkv_h; j = i - n_hs; }
    else if (i < n_hs + n_wqkv + n_wout) { src = wout; dst = wout_h; j = i - n_hs - n_wqkv; }
    else return;
    float4 v = src[j];
    f16x4 o = { (_Float16)v.x, (_Float16)v.y, (_Float16)v.z, (_Float16)v.w };
    dst[j] = o;
}

// ---- GEMM v3: C[M,N] = A[M,GK] @ B[N,GK]^T ----
// BM=BN=128, BK=64; 256 thr / 4 waves (2M x 2N); per-wave 64x64 out.
// 2-ring LDS (64KB -> 2 blocks/CU for block-level overlap) + counted vmcnt(8):
//   vmcnt(8)+barrier (tile t visible; t+1 in flight) -> ds_read -> lgkm0+barrier
//   (all waves' reads done) -> stage(t+2) into just-freed buffer -> MFMA.
// T2 swizzle: pre-swizzled global source, linear LDS dest, XOR(row&7) read.
// MODE 0: scatter to Q/K/V [B][NH][T][HD] fp16, Q scaled by 1/sqrt(HD)
// MODE 1: write fp32 C[M][HID] (= d_out)
template <int MODE>
__global__ __launch_bounds__(256, 2)
void gemm_bt(const _Float16* __restrict__ A, const _Float16* __restrict__ B,
             float* __restrict__ C, _Float16* __restrict__ Qo,
             _Float16* __restrict__ Ko, _Float16* __restrict__ Vo, int NB) {
    __shared__ __align__(16) _Float16 As[2][128 * 64];  // 16KB x2
    __shared__ __align__(16) _Float16 Bs[2][128 * 64];  // 16KB x2 (total 64KB)

    const int tid  = threadIdx.x;
    const int lane = tid & 63;
    const int w    = tid >> 6;        // wave 0..3
    const int l15  = lane & 15;
    const int lq   = lane >> 4;
    const int wr   = w >> 1, wc = w & 1;   // 2M x 2N wave grid

    // T1: XCD-aware block swizzle (gridDim.x % 8 == 0)
    const int bid = (int)blockIdx.x;
    const int cpx = (int)gridDim.x >> 3;
    const int swz = (bid & 7) * cpx + (bid >> 3);
    const int bn  = swz % NB, bm = swz / NB;
    const int m0  = bm * 128, n0 = bn * 128;

    const _Float16* Ab = A + (size_t)m0 * GK;
    const _Float16* Bb = B + (size_t)n0 * GK;

    auto stage = [&](int t, int b) {
        const int k0 = t * 64;
        #pragma unroll
        for (int it = 0; it < 4; ++it) {            // A: 128 rows x 8 chunks of 16B
            const int slot = it * 256 + tid;
            const int row = slot >> 3, c16 = slot & 7;
            const int srcb = c16 ^ (row & 7);       // inverse-swizzled source
            async_copy16(Ab + (size_t)row * GK + k0 + srcb * 8,
                         (char*)As[b] + slot * 16); // linear dest
        }
        #pragma unroll
        for (int it = 0; it < 4; ++it) {            // B: 128 rows x 8 chunks
            const int slot = it * 256 + tid;
            const int row = slot >> 3, c16 = slot & 7;
            const int srcb = c16 ^ (row & 7);
            async_copy16(Bb + (size_t)row * GK + k0 + srcb * 8,
                         (char*)Bs[b] + slot * 16);
        }
    };

    f32x4 acc[4][4] = {};

    stage(0, 0);
    stage(1, 1);

    for (int t = 0; t < NKT; ++t) {
        const int cur = t & 1;
        // outstanding: tile t (8, oldest) + tile t+1 (8) -> keep t+1 in flight
        if (t + 1 < NKT) asm volatile("s_waitcnt vmcnt(8)" ::: "memory");
        else             asm volatile("s_waitcnt vmcnt(0)" ::: "memory");
        __builtin_amdgcn_s_barrier();      // tile t globally visible
        __builtin_amdgcn_sched_barrier(0);

        const char* At_ = (const char*)As[cur];
        const char* Bt_ = (const char*)Bs[cur];

        f16x8 af[4][2], bff[4][2];
        #pragma unroll
        for (int i = 0; i < 4; ++i)
            #pragma unroll
            for (int kk = 0; kk < 2; ++kk) {
                const int ra = wr * 64 + i * 16 + l15;
                af[i][kk]  = *(const f16x8*)(At_ + ra * 128 + (((kk * 4 + lq) ^ (ra & 7)) << 4));
                const int rb = wc * 64 + i * 16 + l15;
                bff[i][kk] = *(const f16x8*)(Bt_ + rb * 128 + (((kk * 4 + lq) ^ (rb & 7)) << 4));
            }
        asm volatile("s_waitcnt lgkmcnt(0)" ::: "memory");
        __builtin_amdgcn_sched_barrier(0);
        __builtin_amdgcn_s_barrier();      // ALL waves done reading buf[cur]
        __builtin_amdgcn_sched_barrier(0);

        if (t + 2 < NKT) stage(t + 2, cur);   // safe overwrite of just-freed buffer

        __builtin_amdgcn_s_setprio(1);
        #pragma unroll
        for (int kk = 0; kk < 2; ++kk)
            #pragma unroll
            for (int i = 0; i < 4; ++i)
                #pragma unroll
                for (int j = 0; j < 4; ++j)
                    acc[i][j] = mfma16(af[i][kk], bff[j][kk], acc[i][j]);
        __builtin_amdgcn_s_setprio(0);
    }

    if (MODE == 0) {
        #pragma unroll
        for (int j = 0; j < 4; ++j) {
            const int ncol = n0 + wc * 64 + j * 16 + l15;
            const int which = ncol >> 11;          // 0=Q 1=K 2=V
            const int oo = ncol & 2047;
            const int head = oo >> 7;
            const int d = oo & 127;
            _Float16* dst = (which == 0) ? Qo : (which == 1) ? Ko : Vo;
            const float scl = (which == 0) ? 0.08838834764831845f : 1.0f;
            #pragma unroll
            for (int i = 0; i < 4; ++i) {
                #pragma unroll
                for (int r = 0; r < 4; ++r) {
                    const int m = m0 + wr * 64 + i * 16 + lq * 4 + r;
                    const int b = m >> 11, tt = m & 2047;
                    dst[((size_t)(b * NH + head) * TSEQ + tt) * HD + d] =
                        (_Float16)(acc[i][j][r] * scl);
                }
            }
        }
    } else {
        #pragma unroll
        for (int i = 0; i < 4; ++i)
            #pragma unroll
            for (int j = 0; j < 4; ++j)
                #pragma unroll
                for (int r = 0; r < 4; ++r) {
                    const int m = m0 + wr * 64 + i * 16 + lq * 4 + r;
                    const int n = n0 + wc * 64 + j * 16 + l15;
                    C[(size_t)m * HID + n] = acc[i][j][r];
                }
    }
}

// ---- causal flash attention v6 (unchanged from R7) ----
// QBLK=64, 4 waves x 16 rows, triangle pairs -> 512 uniform blocks, ones-MFMA sum,
// lazy max, single-buffered Ks/Vt: 40KB LDS -> 4 blocks/CU. Register V-prefetch.
__global__ __launch_bounds__(256)
void attn_fwd(const _Float16* __restrict__ Q, const _Float16* __restrict__ K,
              const _Float16* __restrict__ V, _Float16* __restrict__ O) {
    __shared__ __align__(16) char Ks[64 * 256];   // [64][128] f16, swizzled (16KB)
    __shared__ __align__(16) char Vt[128 * 128];  // [128][64] f16 V^T, swizzled (16KB)
    __shared__ __align__(16) char Ps[4][2048];    // per-wave [16][64] f16 P (8KB)

    const int tid  = threadIdx.x;
    const int lane = tid & 63;
    const int w    = tid >> 6;      // 0..3
    const int l15  = lane & 15;
    const int lq   = lane >> 4;

    const int bh   = (int)blockIdx.x & 31;   // same-bh blocks share XCD (bid&7=bh&7)
    const int pair = (int)blockIdx.x >> 5;   // 0..15
    const int b = bh >> 4, h = bh & 15;

    const size_t base = (size_t)bh * TSEQ * HD;
    const _Float16* Qp = Q + base;
    const _Float16* Kp = K + base;
    const _Float16* Vp = V + base;

    const f16x8 ones = { (_Float16)1.f, (_Float16)1.f, (_Float16)1.f, (_Float16)1.f,
                         (_Float16)1.f, (_Float16)1.f, (_Float16)1.f, (_Float16)1.f };

    uint4 vv[4];
    auto loadV = [&](int t) {   // lane = kv row; wave w owns d-chunks w*4..w*4+3
        const int row = tid & 63;
        #pragma unroll
        for (int it = 0; it < 4; ++it) {
            const int c8 = w * 4 + it;
            vv[it] = *(const uint4*)(Vp + (size_t)(t * 64 + row) * HD + c8 * 8);
        }
    };
    auto stageK = [&](int t) {
        #pragma unroll
        for (int it = 0; it < 4; ++it) {
            const int slot = it * 256 + tid;
            const int row = slot >> 4, c16 = slot & 15;
            const int srcb = c16 ^ (row & 7);
            async_copy16(Kp + (size_t)(t * 64 + row) * HD + srcb * 8, Ks + slot * 16);
        }
    };
    auto writeV = [&]() {   // ushort stores at d*128 + row*2: 2-way, free
        const int row = tid & 63;
        #pragma unroll
        for (int it = 0; it < 4; ++it) {
            const int c8 = w * 4 + it;
            const uint32_t wrd[4] = {vv[it].x, vv[it].y, vv[it].z, vv[it].w};
            #pragma unroll
            for (int p2 = 0; p2 < 4; ++p2) {
                const int d0 = c8 * 8 + p2 * 2, d1 = d0 + 1;
                int b0 = d0 * 128 + row * 2; b0 ^= (d0 & 7) << 4;
                int b1 = d1 * 128 + row * 2; b1 ^= (d1 & 7) << 4;
                *(ushort_t*)(Vt + b0) = (ushort_t)(wrd[p2] & 0xffffu);
                *(ushort_t*)(Vt + b1) = (ushort_t)(wrd[p2] >> 16);
            }
        }
    };

    char* Pb = Ps[w];

    for (int phase = 0; phase < 2; ++phase) {
        const int qt = phase ? pair : (31 - pair);
        const int q0 = qt * 64;
        const int NT = qt + 1;

        if (phase) __syncthreads();   // all waves done with phase-0 LDS before reuse

        const int qrow = q0 + w * 16 + l15;
        f16x8 qf[4];
        #pragma unroll
        for (int ks = 0; ks < 4; ++ks)
            qf[ks] = *(const f16x8*)(Qp + (size_t)qrow * HD + ks * 32 + lq * 8);

        f32x4 o[8] = {};
        f32x4 osum = {};
        float m_run[4];
        #pragma unroll
        for (int r = 0; r < 4; ++r) m_run[r] = -1e30f;

        stageK(0);      // async into Ks (safe: phase barrier / fresh start)
        loadV(0);       // register prefetch

        for (int t = 0; t < NT; ++t) {
            writeV();             // vv(t) -> Vt (readers of t-1 drained at barrier A)
            __syncthreads();      // barrier B: stageK(t) drained + writeV visible
            if (t + 1 < NT) loadV(t + 1);   // register prefetch under compute

            const int kv0 = t * 64;
            // S = Q K^T
            f32x4 s[4] = {};
            __builtin_amdgcn_s_setprio(1);
            #pragma unroll
            for (int ks = 0; ks < 4; ++ks) {
                #pragma unroll
                for (int nf = 0; nf < 4; ++nf) {
                    const int r   = nf * 16 + l15;
                    const int blk = (ks * 4 + lq) ^ (r & 7);
                    const f16x8 kf = *(const f16x8*)(Ks + r * 256 + blk * 16);
                    s[nf] = mfma16(qf[ks], kf, s[nf]);
                }
            }
            __builtin_amdgcn_s_setprio(0);

            if (kv0 + 63 > q0 + w * 16) {   // diagonal-crossing for this wave
                #pragma unroll
                for (int nf = 0; nf < 4; ++nf) {
                    const int kvp = kv0 + nf * 16 + l15;
                    #pragma unroll
                    for (int r = 0; r < 4; ++r)
                        if (kvp > q0 + w * 16 + lq * 4 + r) s[nf][r] = -1e30f;
                }
            }

            // lazy max: local check; full shuffle-reduce only when triggered
            bool need = false;
            #pragma unroll
            for (int r = 0; r < 4; ++r) {
                const float v = fmaxf(fmaxf(s[0][r], s[1][r]), fmaxf(s[2][r], s[3][r]));
                need = need || (v > m_run[r] + 5.0f);
            }
            if (__any(need)) {
                float alpha[4];
                #pragma unroll
                for (int r = 0; r < 4; ++r) {
                    float v = fmaxf(fmaxf(s[0][r], s[1][r]), fmaxf(s[2][r], s[3][r]));
                    v = fmaxf(v, __shfl_xor(v, 1));
                    v = fmaxf(v, __shfl_xor(v, 2));
                    v = fmaxf(v, __shfl_xor(v, 4));
                    v = fmaxf(v, __shfl_xor(v, 8));
                    const float mn = fmaxf(m_run[r], v);
                    alpha[r] = __builtin_exp2f((m_run[r] - mn) * LOG2E);
                    m_run[r] = mn;
                }
                #pragma unroll
                for (int df = 0; df < 8; ++df)
                    #pragma unroll
                    for (int r = 0; r < 4; ++r)
                        o[df][r] *= alpha[r];
                #pragma unroll
                for (int r = 0; r < 4; ++r) osum[r] *= alpha[r];
            }

            // P = exp(S - m) -> wave-private LDS (f16)
            #pragma unroll
            for (int nf = 0; nf < 4; ++nf) {
                #pragma unroll
                for (int r = 0; r < 4; ++r) {
                    const float p = __builtin_exp2f((s[nf][r] - m_run[r]) * LOG2E);
                    const int qp = lq * 4 + r;
                    int byt = qp * 128 + (nf * 16 + l15) * 2;
                    byt ^= (qp & 7) << 4;
                    union { _Float16 hf; ushort_t u; } cv;
                    cv.hf = (_Float16)p;
                    *(ushort_t*)(Pb + byt) = cv.u;   // wave-private, in-order LDS
                }
            }

            // O += P @ V ; osum += P @ 1
            __builtin_amdgcn_s_setprio(1);
            #pragma unroll
            for (int ks2 = 0; ks2 < 2; ++ks2) {
                const int pblk = (ks2 * 4 + lq) ^ (l15 & 7);
                const f16x8 pf = *(const f16x8*)(Pb + l15 * 128 + pblk * 16);
                #pragma unroll
                for (int df = 0; df < 8; ++df) {
                    const int vr   = df * 16 + l15;
                    const int vblk = (ks2 * 4 + lq) ^ (vr & 7);
                    const f16x8 vf = *(const f16x8*)(Vt + vr * 128 + vblk * 16);
                    o[df] = mfma16(pf, vf, o[df]);
                }
                osum = mfma16(pf, ones, osum);
            }
            __builtin_amdgcn_s_setprio(0);

            if (t + 1 < NT) {
                __syncthreads();     // barrier A: all waves done reading Ks/Vt(t)
                stageK(t + 1);       // async overwrite of Ks; drains at next barrier B
            }
        }

        float rl[4];
        #pragma unroll
        for (int r = 0; r < 4; ++r) rl[r] = 1.0f / osum[r];
        #pragma unroll
        for (int df = 0; df < 8; ++df) {
            #pragma unroll
            for (int r = 0; r < 4; ++r) {
                const int qg = q0 + w * 16 + lq * 4 + r;
                const int dg = df * 16 + l15;
                O[((size_t)(b * TSEQ + qg)) * HID + h * HD + dg] =
                    (_Float16)(o[df][r] * rl[r]);
            }
        }
    }
}

extern "C" void kernel_launch(void* const* d_in, const int* in_sizes, int n_in,
                              void* d_out, int out_size, void* d_ws, size_t ws_size,
                              hipStream_t stream) {
    (void)in_sizes; (void)n_in; (void)out_size; (void)ws_size;
    const float* hs   = (const float*)d_in[0];
    const float* wqkv = (const float*)d_in[1];
    const float* wout = (const float*)d_in[2];

    char* ws = (char*)d_ws;
    size_t off = 0;
    _Float16* hs_h   = (_Float16*)(ws + off); off += (size_t)BATCH * TSEQ * HID * 2;
    _Float16* wqkv_h = (_Float16*)(ws + off); off += (size_t)3 * HID * HID * 2;
    _Float16* wout_h = (_Float16*)(ws + off); off += (size_t)HID * HID * 2;
    _Float16* Qh     = (_Float16*)(ws + off); off += (size_t)BATCH * NH * TSEQ * HD * 2;
    _Float16* Kh     = (_Float16*)(ws + off); off += (size_t)BATCH * NH * TSEQ * HD * 2;
    _Float16* Vh     = (_Float16*)(ws + off); off += (size_t)BATCH * NH * TSEQ * HD * 2;
    _Float16* At     = (_Float16*)(ws + off); off += (size_t)BATCH * TSEQ * HID * 2;

    const int n4_hs   = BATCH * TSEQ * HID / 4;
    const int n4_wqkv = 3 * HID * HID / 4;
    const int n4_wout = HID * HID / 4;
    const int n4_all  = n4_hs + n4_wqkv + n4_wout;
    cast_all<<<dim3((n4_all + 255) / 256), dim3(256), 0, stream>>>(
        (const float4*)hs, (const float4*)wqkv, (const float4*)wout,
        (f16x4*)hs_h, (f16x4*)wqkv_h, (f16x4*)wout_h, n4_hs, n4_wqkv, n4_wout);

    // GEMM1: M=4096, N=6144: grid 32x48 = 1536 blocks (perfect 6 rounds @ 2/CU)
    gemm_bt<0><<<dim3(1536), dim3(256), 0, stream>>>(
        hs_h, wqkv_h, nullptr, Qh, Kh, Vh, 48);

    attn_fwd<<<dim3(512), dim3(256), 0, stream>>>(Qh, Kh, Vh, At);

    // GEMM2: M=4096, N=2048: grid 32x16 = 512 blocks (perfect 2 rounds @ 2/CU)
    gemm_bt<1><<<dim3(512), dim3(256), 0, stream>>>(
        At, wout_h, (float*)d_out, nullptr, nullptr, nullptr, 16);
}

// Round 9
// 262.859 us; speedup vs baseline: 1.0781x; 1.0112x over previous
//
#include <hip/hip_runtime.h>
#include <cstdint>
#include <cstddef>

// ---- types ----
typedef _Float16 f16x8 __attribute__((ext_vector_type(8)));
typedef _Float16 f16x4 __attribute__((ext_vector_type(4)));
typedef float    f32x4 __attribute__((ext_vector_type(4)));
typedef unsigned short ushort_t;

#define LOG2E 1.4426950408889634f

constexpr int BATCH = 2;
constexpr int TSEQ  = 2048;
constexpr int HID   = 2048;
constexpr int NH    = 16;
constexpr int HD    = 128;
constexpr int GK    = 2048;   // K-dim of both GEMMs
constexpr int NKT   = GK / 64; // 32 K-tiles

__device__ inline f32x4 mfma16(f16x8 a, f16x8 b, f32x4 c) {
    return __builtin_amdgcn_mfma_f32_16x16x32_f16(a, b, c, 0, 0, 0);
}

// async global->LDS, 16B per lane; LDS dest must be linear (base + lane*16)
__device__ inline void async_copy16(const void* src, void* dst_lds) {
    __builtin_amdgcn_global_load_lds(
        (const __attribute__((address_space(1))) uint32_t*)src,
        (__attribute__((address_space(3))) uint32_t*)dst_lds, 16, 0, 0);
}

// ---- fp32 -> fp16 cast, all three tensors in one launch ----
__global__ __launch_bounds__(256)
void cast_all(const float4* __restrict__ hs, const float4* __restrict__ wqkv,
              const float4* __restrict__ wout, f16x4* __restrict__ hs_h,
              f16x4* __restrict__ wqkv_h, f16x4* __restrict__ wout_h,
              int n_hs, int n_wqkv, int n_wout) {
    int i = blockIdx.x * 256 + threadIdx.x;
    const float4* src; f16x4* dst; int j;
    if (i < n_hs)                 { src = hs;   dst = hs_h;   j = i; }
    else if (i < n_hs + n_wqkv)   { src = wqkv; dst = wqkv_h; j = i - n_hs; }
    else if (i < n_hs + n_wqkv + n_wout) { src = wout; dst = wout_h; j = i - n_hs - n_wqkv; }
    else return;
    float4 v = src[j];
    f16x4 o = { (_Float16)v.x, (_Float16)v.y, (_Float16)v.z, (_Float16)v.w };
    dst[j] = o;
}

// ---- GEMM big (R7-proven, 110 µs on gemm0): BM=256, BN=128, BK=64; 512 thr /
// 8 waves (4M x 2N); 3-ring LDS + counted vmcnt(6); T2 swizzle; T1 XCD swizzle.
// MODE 0: scatter to Q/K/V [B][NH][T][HD] fp16, Q scaled by 1/sqrt(HD)
template <int MODE>
__global__ __launch_bounds__(512, 2)
void gemm_big(const _Float16* __restrict__ A, const _Float16* __restrict__ B,
              float* __restrict__ C, _Float16* __restrict__ Qo,
              _Float16* __restrict__ Ko, _Float16* __restrict__ Vo, int NB) {
    __shared__ __align__(16) _Float16 As[3][256 * 64];
    __shared__ __align__(16) _Float16 Bs[3][128 * 64];

    const int tid  = threadIdx.x;
    const int lane = tid & 63;
    const int w    = tid >> 6;
    const int l15  = lane & 15;
    const int lq   = lane >> 4;
    const int wr   = w >> 1, wc = w & 1;

    const int bid = (int)blockIdx.x;
    const int cpx = (int)gridDim.x >> 3;
    const int swz = (bid & 7) * cpx + (bid >> 3);
    const int bn  = swz % NB, bm = swz / NB;
    const int m0  = bm * 256, n0 = bn * 128;

    const _Float16* Ab = A + (size_t)m0 * GK;
    const _Float16* Bb = B + (size_t)n0 * GK;

    auto stage = [&](int t, int b) {
        const int k0 = t * 64;
        #pragma unroll
        for (int it = 0; it < 4; ++it) {
            const int slot = it * 512 + tid;
            const int row = slot >> 3, c16 = slot & 7;
            const int srcb = c16 ^ (row & 7);
            async_copy16(Ab + (size_t)row * GK + k0 + srcb * 8,
                         (char*)As[b] + slot * 16);
        }
        #pragma unroll
        for (int it = 0; it < 2; ++it) {
            const int slot = it * 512 + tid;
            const int row = slot >> 3, c16 = slot & 7;
            const int srcb = c16 ^ (row & 7);
            async_copy16(Bb + (size_t)row * GK + k0 + srcb * 8,
                         (char*)Bs[b] + slot * 16);
        }
    };

    f32x4 acc[4][4] = {};

    stage(0, 0);
    stage(1, 1);

    for (int t = 0; t < NKT; ++t) {
        if (t + 1 < NKT) asm volatile("s_waitcnt vmcnt(6)" ::: "memory");
        else             asm volatile("s_waitcnt vmcnt(0)" ::: "memory");
        __builtin_amdgcn_s_barrier();
        __builtin_amdgcn_sched_barrier(0);

        const char* At_ = (const char*)As[t % 3];
        const char* Bt_ = (const char*)Bs[t % 3];

        f16x8 af[4][2], bff[4][2];
        #pragma unroll
        for (int i = 0; i < 4; ++i)
            #pragma unroll
            for (int kk = 0; kk < 2; ++kk) {
                const int ra = wr * 64 + i * 16 + l15;
                af[i][kk]  = *(const f16x8*)(At_ + ra * 128 + (((kk * 4 + lq) ^ (ra & 7)) << 4));
                const int rb = wc * 64 + i * 16 + l15;
                bff[i][kk] = *(const f16x8*)(Bt_ + rb * 128 + (((kk * 4 + lq) ^ (rb & 7)) << 4));
            }

        if (t + 2 < NKT) stage(t + 2, (t + 2) % 3);

        __builtin_amdgcn_s_setprio(1);
        #pragma unroll
        for (int kk = 0; kk < 2; ++kk)
            #pragma unroll
            for (int i = 0; i < 4; ++i)
                #pragma unroll
                for (int j = 0; j < 4; ++j)
                    acc[i][j] = mfma16(af[i][kk], bff[j][kk], acc[i][j]);
        __builtin_amdgcn_s_setprio(0);
    }

    if (MODE == 0) {
        #pragma unroll
        for (int j = 0; j < 4; ++j) {
            const int ncol = n0 + wc * 64 + j * 16 + l15;
            const int which = ncol >> 11;
            const int oo = ncol & 2047;
            const int head = oo >> 7;
            const int d = oo & 127;
            _Float16* dst = (which == 0) ? Qo : (which == 1) ? Ko : Vo;
            const float scl = (which == 0) ? 0.08838834764831845f : 1.0f;
            #pragma unroll
            for (int i = 0; i < 4; ++i) {
                #pragma unroll
                for (int r = 0; r < 4; ++r) {
                    const int m = m0 + wr * 64 + i * 16 + lq * 4 + r;
                    const int b = m >> 11, tt = m & 2047;
                    dst[((size_t)(b * NH + head) * TSEQ + tt) * HD + d] =
                        (_Float16)(acc[i][j][r] * scl);
                }
            }
        }
    } else {
        #pragma unroll
        for (int i = 0; i < 4; ++i)
            #pragma unroll
            for (int j = 0; j < 4; ++j)
                #pragma unroll
                for (int r = 0; r < 4; ++r) {
                    const int m = m0 + wr * 64 + i * 16 + lq * 4 + r;
                    const int n = n0 + wc * 64 + j * 16 + l15;
                    C[(size_t)m * HID + n] = acc[i][j][r];
                }
    }
}

// ---- GEMM small (R8-proven on out-proj): BM=BN=128, BK=64; 256 thr / 4 waves;
// 2-ring LDS (64KB -> 2 blocks/CU) + counted vmcnt(8). Used for MODE 1 only.
template <int MODE>
__global__ __launch_bounds__(256, 2)
void gemm_small(const _Float16* __restrict__ A, const _Float16* __restrict__ B,
                float* __restrict__ C, int NB) {
    __shared__ __align__(16) _Float16 As[2][128 * 64];
    __shared__ __align__(16) _Float16 Bs[2][128 * 64];

    const int tid  = threadIdx.x;
    const int lane = tid & 63;
    const int w    = tid >> 6;
    const int l15  = lane & 15;
    const int lq   = lane >> 4;
    const int wr   = w >> 1, wc = w & 1;

    const int bid = (int)blockIdx.x;
    const int cpx = (int)gridDim.x >> 3;
    const int swz = (bid & 7) * cpx + (bid >> 3);
    const int bn  = swz % NB, bm = swz / NB;
    const int m0  = bm * 128, n0 = bn * 128;

    const _Float16* Ab = A + (size_t)m0 * GK;
    const _Float16* Bb = B + (size_t)n0 * GK;

    auto stage = [&](int t, int b) {
        const int k0 = t * 64;
        #pragma unroll
        for (int it = 0; it < 4; ++it) {
            const int slot = it * 256 + tid;
            const int row = slot >> 3, c16 = slot & 7;
            const int srcb = c16 ^ (row & 7);
            async_copy16(Ab + (size_t)row * GK + k0 + srcb * 8,
                         (char*)As[b] + slot * 16);
        }
        #pragma unroll
        for (int it = 0; it < 4; ++it) {
            const int slot = it * 256 + tid;
            const int row = slot >> 3, c16 = slot & 7;
            const int srcb = c16 ^ (row & 7);
            async_copy16(Bb + (size_t)row * GK + k0 + srcb * 8,
                         (char*)Bs[b] + slot * 16);
        }
    };

    f32x4 acc[4][4] = {};

    stage(0, 0);
    stage(1, 1);

    for (int t = 0; t < NKT; ++t) {
        const int cur = t & 1;
        if (t + 1 < NKT) asm volatile("s_waitcnt vmcnt(8)" ::: "memory");
        else             asm volatile("s_waitcnt vmcnt(0)" ::: "memory");
        __builtin_amdgcn_s_barrier();
        __builtin_amdgcn_sched_barrier(0);

        const char* At_ = (const char*)As[cur];
        const char* Bt_ = (const char*)Bs[cur];

        f16x8 af[4][2], bff[4][2];
        #pragma unroll
        for (int i = 0; i < 4; ++i)
            #pragma unroll
            for (int kk = 0; kk < 2; ++kk) {
                const int ra = wr * 64 + i * 16 + l15;
                af[i][kk]  = *(const f16x8*)(At_ + ra * 128 + (((kk * 4 + lq) ^ (ra & 7)) << 4));
                const int rb = wc * 64 + i * 16 + l15;
                bff[i][kk] = *(const f16x8*)(Bt_ + rb * 128 + (((kk * 4 + lq) ^ (rb & 7)) << 4));
            }
        asm volatile("s_waitcnt lgkmcnt(0)" ::: "memory");
        __builtin_amdgcn_sched_barrier(0);
        __builtin_amdgcn_s_barrier();
        __builtin_amdgcn_sched_barrier(0);

        if (t + 2 < NKT) stage(t + 2, cur);

        __builtin_amdgcn_s_setprio(1);
        #pragma unroll
        for (int kk = 0; kk < 2; ++kk)
            #pragma unroll
            for (int i = 0; i < 4; ++i)
                #pragma unroll
                for (int j = 0; j < 4; ++j)
                    acc[i][j] = mfma16(af[i][kk], bff[j][kk], acc[i][j]);
        __builtin_amdgcn_s_setprio(0);
    }

    #pragma unroll
    for (int i = 0; i < 4; ++i)
        #pragma unroll
        for (int j = 0; j < 4; ++j)
            #pragma unroll
            for (int r = 0; r < 4; ++r) {
                const int m = m0 + wr * 64 + i * 16 + lq * 4 + r;
                const int n = n0 + wc * 64 + j * 16 + l15;
                C[(size_t)m * HID + n] = acc[i][j][r];
            }
}

// ---- causal flash attention v6 (unchanged) ----
__global__ __launch_bounds__(256)
void attn_fwd(const _Float16* __restrict__ Q, const _Float16* __restrict__ K,
              const _Float16* __restrict__ V, _Float16* __restrict__ O) {
    __shared__ __align__(16) char Ks[64 * 256];   // [64][128] f16, swizzled (16KB)
    __shared__ __align__(16) char Vt[128 * 128];  // [128][64] f16 V^T, swizzled (16KB)
    __shared__ __align__(16) char Ps[4][2048];    // per-wave [16][64] f16 P (8KB)

    const int tid  = threadIdx.x;
    const int lane = tid & 63;
    const int w    = tid >> 6;      // 0..3
    const int l15  = lane & 15;
    const int lq   = lane >> 4;

    const int bh   = (int)blockIdx.x & 31;
    const int pair = (int)blockIdx.x >> 5;   // 0..15
    const int b = bh >> 4, h = bh & 15;

    const size_t base = (size_t)bh * TSEQ * HD;
    const _Float16* Qp = Q + base;
    const _Float16* Kp = K + base;
    const _Float16* Vp = V + base;

    const f16x8 ones = { (_Float16)1.f, (_Float16)1.f, (_Float16)1.f, (_Float16)1.f,
                         (_Float16)1.f, (_Float16)1.f, (_Float16)1.f, (_Float16)1.f };

    uint4 vv[4];
    auto loadV = [&](int t) {
        const int row = tid & 63;
        #pragma unroll
        for (int it = 0; it < 4; ++it) {
            const int c8 = w * 4 + it;
            vv[it] = *(const uint4*)(Vp + (size_t)(t * 64 + row) * HD + c8 * 8);
        }
    };
    auto stageK = [&](int t) {
        #pragma unroll
        for (int it = 0; it < 4; ++it) {
            const int slot = it * 256 + tid;
            const int row = slot >> 4, c16 = slot & 15;
            const int srcb = c16 ^ (row & 7);
            async_copy16(Kp + (size_t)(t * 64 + row) * HD + srcb * 8, Ks + slot * 16);
        }
    };
    auto writeV = [&]() {
        const int row = tid & 63;
        #pragma unroll
        for (int it = 0; it < 4; ++it) {
            const int c8 = w * 4 + it;
            const uint32_t wrd[4] = {vv[it].x, vv[it].y, vv[it].z, vv[it].w};
            #pragma unroll
            for (int p2 = 0; p2 < 4; ++p2) {
                const int d0 = c8 * 8 + p2 * 2, d1 = d0 + 1;
                int b0 = d0 * 128 + row * 2; b0 ^= (d0 & 7) << 4;
                int b1 = d1 * 128 + row * 2; b1 ^= (d1 & 7) << 4;
                *(ushort_t*)(Vt + b0) = (ushort_t)(wrd[p2] & 0xffffu);
                *(ushort_t*)(Vt + b1) = (ushort_t)(wrd[p2] >> 16);
            }
        }
    };

    char* Pb = Ps[w];

    for (int phase = 0; phase < 2; ++phase) {
        const int qt = phase ? pair : (31 - pair);
        const int q0 = qt * 64;
        const int NT = qt + 1;

        if (phase) __syncthreads();

        const int qrow = q0 + w * 16 + l15;
        f16x8 qf[4];
        #pragma unroll
        for (int ks = 0; ks < 4; ++ks)
            qf[ks] = *(const f16x8*)(Qp + (size_t)qrow * HD + ks * 32 + lq * 8);

        f32x4 o[8] = {};
        f32x4 osum = {};
        float m_run[4];
        #pragma unroll
        for (int r = 0; r < 4; ++r) m_run[r] = -1e30f;

        stageK(0);
        loadV(0);

        for (int t = 0; t < NT; ++t) {
            writeV();
            __syncthreads();
            if (t + 1 < NT) loadV(t + 1);

            const int kv0 = t * 64;
            f32x4 s[4] = {};
            __builtin_amdgcn_s_setprio(1);
            #pragma unroll
            for (int ks = 0; ks < 4; ++ks) {
                #pragma unroll
                for (int nf = 0; nf < 4; ++nf) {
                    const int r   = nf * 16 + l15;
                    const int blk = (ks * 4 + lq) ^ (r & 7);
                    const f16x8 kf = *(const f16x8*)(Ks + r * 256 + blk * 16);
                    s[nf] = mfma16(qf[ks], kf, s[nf]);
                }
            }
            __builtin_amdgcn_s_setprio(0);

            if (kv0 + 63 > q0 + w * 16) {
                #pragma unroll
                for (int nf = 0; nf < 4; ++nf) {
                    const int kvp = kv0 + nf * 16 + l15;
                    #pragma unroll
                    for (int r = 0; r < 4; ++r)
                        if (kvp > q0 + w * 16 + lq * 4 + r) s[nf][r] = -1e30f;
                }
            }

            bool need = false;
            #pragma unroll
            for (int r = 0; r < 4; ++r) {
                const float v = fmaxf(fmaxf(s[0][r], s[1][r]), fmaxf(s[2][r], s[3][r]));
                need = need || (v > m_run[r] + 5.0f);
            }
            if (__any(need)) {
                float alpha[4];
                #pragma unroll
                for (int r = 0; r < 4; ++r) {
                    float v = fmaxf(fmaxf(s[0][r], s[1][r]), fmaxf(s[2][r], s[3][r]));
                    v = fmaxf(v, __shfl_xor(v, 1));
                    v = fmaxf(v, __shfl_xor(v, 2));
                    v = fmaxf(v, __shfl_xor(v, 4));
                    v = fmaxf(v, __shfl_xor(v, 8));
                    const float mn = fmaxf(m_run[r], v);
                    alpha[r] = __builtin_exp2f((m_run[r] - mn) * LOG2E);
                    m_run[r] = mn;
                }
                #pragma unroll
                for (int df = 0; df < 8; ++df)
                    #pragma unroll
                    for (int r = 0; r < 4; ++r)
                        o[df][r] *= alpha[r];
                #pragma unroll
                for (int r = 0; r < 4; ++r) osum[r] *= alpha[r];
            }

            #pragma unroll
            for (int nf = 0; nf < 4; ++nf) {
                #pragma unroll
                for (int r = 0; r < 4; ++r) {
                    const float p = __builtin_exp2f((s[nf][r] - m_run[r]) * LOG2E);
                    const int qp = lq * 4 + r;
                    int byt = qp * 128 + (nf * 16 + l15) * 2;
                    byt ^= (qp & 7) << 4;
                    union { _Float16 hf; ushort_t u; } cv;
                    cv.hf = (_Float16)p;
                    *(ushort_t*)(Pb + byt) = cv.u;
                }
            }

            __builtin_amdgcn_s_setprio(1);
            #pragma unroll
            for (int ks2 = 0; ks2 < 2; ++ks2) {
                const int pblk = (ks2 * 4 + lq) ^ (l15 & 7);
                const f16x8 pf = *(const f16x8*)(Pb + l15 * 128 + pblk * 16);
                #pragma unroll
                for (int df = 0; df < 8; ++df) {
                    const int vr   = df * 16 + l15;
                    const int vblk = (ks2 * 4 + lq) ^ (vr & 7);
                    const f16x8 vf = *(const f16x8*)(Vt + vr * 128 + vblk * 16);
                    o[df] = mfma16(pf, vf, o[df]);
                }
                osum = mfma16(pf, ones, osum);
            }
            __builtin_amdgcn_s_setprio(0);

            if (t + 1 < NT) {
                __syncthreads();
                stageK(t + 1);
            }
        }

        float rl[4];
        #pragma unroll
        for (int r = 0; r < 4; ++r) rl[r] = 1.0f / osum[r];
        #pragma unroll
        for (int df = 0; df < 8; ++df) {
            #pragma unroll
            for (int r = 0; r < 4; ++r) {
                const int qg = q0 + w * 16 + lq * 4 + r;
                const int dg = df * 16 + l15;
                O[((size_t)(b * TSEQ + qg)) * HID + h * HD + dg] =
                    (_Float16)(o[df][r] * rl[r]);
            }
        }
    }
}

extern "C" void kernel_launch(void* const* d_in, const int* in_sizes, int n_in,
                              void* d_out, int out_size, void* d_ws, size_t ws_size,
                              hipStream_t stream) {
    (void)in_sizes; (void)n_in; (void)out_size; (void)ws_size;
    const float* hs   = (const float*)d_in[0];
    const float* wqkv = (const float*)d_in[1];
    const float* wout = (const float*)d_in[2];

    char* ws = (char*)d_ws;
    size_t off = 0;
    _Float16* hs_h   = (_Float16*)(ws + off); off += (size_t)BATCH * TSEQ * HID * 2;
    _Float16* wqkv_h = (_Float16*)(ws + off); off += (size_t)3 * HID * HID * 2;
    _Float16* wout_h = (_Float16*)(ws + off); off += (size_t)HID * HID * 2;
    _Float16* Qh     = (_Float16*)(ws + off); off += (size_t)BATCH * NH * TSEQ * HD * 2;
    _Float16* Kh     = (_Float16*)(ws + off); off += (size_t)BATCH * NH * TSEQ * HD * 2;
    _Float16* Vh     = (_Float16*)(ws + off); off += (size_t)BATCH * NH * TSEQ * HD * 2;
    _Float16* At     = (_Float16*)(ws + off); off += (size_t)BATCH * TSEQ * HID * 2;

    const int n4_hs   = BATCH * TSEQ * HID / 4;
    const int n4_wqkv = 3 * HID * HID / 4;
    const int n4_wout = HID * HID / 4;
    const int n4_all  = n4_hs + n4_wqkv + n4_wout;
    cast_all<<<dim3((n4_all + 255) / 256), dim3(256), 0, stream>>>(
        (const float4*)hs, (const float4*)wqkv, (const float4*)wout,
        (f16x4*)hs_h, (f16x4*)wqkv_h, (f16x4*)wout_h, n4_hs, n4_wqkv, n4_wout);

    // GEMM1: M=4096, N=6144: BM=256 -> grid 16x48 = 768 blocks (R7-proven config)
    gemm_big<0><<<dim3(768), dim3(512), 0, stream>>>(
        hs_h, wqkv_h, nullptr, Qh, Kh, Vh, 48);

    attn_fwd<<<dim3(512), dim3(256), 0, stream>>>(Qh, Kh, Vh, At);

    // GEMM2: M=4096, N=2048: 128^2 -> grid 32x16 = 512 blocks (R8-proven config)
    gemm_small<1><<<dim3(512), dim3(256), 0, stream>>>(
        At, wout_h, (float*)d_out, 16);
}

// Round 11
// 262.258 us; speedup vs baseline: 1.0805x; 1.0023x over previous
//
#include <hip/hip_runtime.h>
#include <cstdint>
#include <cstddef>

// ---- types ----
typedef _Float16 f16x8 __attribute__((ext_vector_type(8)));
typedef _Float16 f16x4 __attribute__((ext_vector_type(4)));
typedef float    f32x4 __attribute__((ext_vector_type(4)));
typedef unsigned short ushort_t;

#define LOG2E 1.4426950408889634f

constexpr int BATCH = 2;
constexpr int TSEQ  = 2048;
constexpr int HID   = 2048;
constexpr int NH    = 16;
constexpr int HD    = 128;
constexpr int GK    = 2048;   // K-dim of both GEMMs
constexpr int NKT   = GK / 64; // 32 K-tiles

__device__ inline f32x4 mfma16(f16x8 a, f16x8 b, f32x4 c) {
    return __builtin_amdgcn_mfma_f32_16x16x32_f16(a, b, c, 0, 0, 0);
}

// async global->LDS, 16B per lane; LDS dest must be linear (base + lane*16)
__device__ inline void async_copy16(const void* src, void* dst_lds) {
    __builtin_amdgcn_global_load_lds(
        (const __attribute__((address_space(1))) uint32_t*)src,
        (__attribute__((address_space(3))) uint32_t*)dst_lds, 16, 0, 0);
}

// v_cvt_pkrtz_f16_f32: pack 2 floats to 2 f16 in one u32.
// NB: builtin returns __fp16 ext_vector(2) on gfx950 -> use decltype in union.
__device__ inline uint32_t pkrtz(float a, float b) {
    union { decltype(__builtin_amdgcn_cvt_pkrtz(0.f, 0.f)) h; uint32_t u; } cv;
    cv.h = __builtin_amdgcn_cvt_pkrtz(a, b);
    return cv.u;
}

// ---- fp32 -> fp16 cast, all three tensors in one launch ----
__global__ __launch_bounds__(256)
void cast_all(const float4* __restrict__ hs, const float4* __restrict__ wqkv,
              const float4* __restrict__ wout, f16x4* __restrict__ hs_h,
              f16x4* __restrict__ wqkv_h, f16x4* __restrict__ wout_h,
              int n_hs, int n_wqkv, int n_wout) {
    int i = blockIdx.x * 256 + threadIdx.x;
    const float4* src; f16x4* dst; int j;
    if (i < n_hs)                 { src = hs;   dst = hs_h;   j = i; }
    else if (i < n_hs + n_wqkv)   { src = wqkv; dst = wqkv_h; j = i - n_hs; }
    else if (i < n_hs + n_wqkv + n_wout) { src = wout; dst = wout_h; j = i - n_hs - n_wqkv; }
    else return;
    float4 v = src[j];
    f16x4 o = { (_Float16)v.x, (_Float16)v.y, (_Float16)v.z, (_Float16)v.w };
    dst[j] = o;
}

// ---- GEMM big (R7/R9-proven): BM=256, BN=128, BK=64; 512 thr / 8 waves;
// 3-ring LDS + counted vmcnt(6); T2 swizzle; T1 XCD swizzle. ----
template <int MODE>
__global__ __launch_bounds__(512, 2)
void gemm_big(const _Float16* __restrict__ A, const _Float16* __restrict__ B,
              float* __restrict__ C, _Float16* __restrict__ Qo,
              _Float16* __restrict__ Ko, _Float16* __restrict__ Vo, int NB) {
    __shared__ __align__(16) _Float16 As[3][256 * 64];
    __shared__ __align__(16) _Float16 Bs[3][128 * 64];

    const int tid  = threadIdx.x;
    const int lane = tid & 63;
    const int w    = tid >> 6;
    const int l15  = lane & 15;
    const int lq   = lane >> 4;
    const int wr   = w >> 1, wc = w & 1;

    const int bid = (int)blockIdx.x;
    const int cpx = (int)gridDim.x >> 3;
    const int swz = (bid & 7) * cpx + (bid >> 3);
    const int bn  = swz % NB, bm = swz / NB;
    const int m0  = bm * 256, n0 = bn * 128;

    const _Float16* Ab = A + (size_t)m0 * GK;
    const _Float16* Bb = B + (size_t)n0 * GK;

    auto stage = [&](int t, int b) {
        const int k0 = t * 64;
        #pragma unroll
        for (int it = 0; it < 4; ++it) {
            const int slot = it * 512 + tid;
            const int row = slot >> 3, c16 = slot & 7;
            const int srcb = c16 ^ (row & 7);
            async_copy16(Ab + (size_t)row * GK + k0 + srcb * 8,
                         (char*)As[b] + slot * 16);
        }
        #pragma unroll
        for (int it = 0; it < 2; ++it) {
            const int slot = it * 512 + tid;
            const int row = slot >> 3, c16 = slot & 7;
            const int srcb = c16 ^ (row & 7);
            async_copy16(Bb + (size_t)row * GK + k0 + srcb * 8,
                         (char*)Bs[b] + slot * 16);
        }
    };

    f32x4 acc[4][4] = {};

    stage(0, 0);
    stage(1, 1);

    for (int t = 0; t < NKT; ++t) {
        if (t + 1 < NKT) asm volatile("s_waitcnt vmcnt(6)" ::: "memory");
        else             asm volatile("s_waitcnt vmcnt(0)" ::: "memory");
        __builtin_amdgcn_s_barrier();
        __builtin_amdgcn_sched_barrier(0);

        const char* At_ = (const char*)As[t % 3];
        const char* Bt_ = (const char*)Bs[t % 3];

        f16x8 af[4][2], bff[4][2];
        #pragma unroll
        for (int i = 0; i < 4; ++i)
            #pragma unroll
            for (int kk = 0; kk < 2; ++kk) {
                const int ra = wr * 64 + i * 16 + l15;
                af[i][kk]  = *(const f16x8*)(At_ + ra * 128 + (((kk * 4 + lq) ^ (ra & 7)) << 4));
                const int rb = wc * 64 + i * 16 + l15;
                bff[i][kk] = *(const f16x8*)(Bt_ + rb * 128 + (((kk * 4 + lq) ^ (rb & 7)) << 4));
            }

        if (t + 2 < NKT) stage(t + 2, (t + 2) % 3);

        __builtin_amdgcn_s_setprio(1);
        #pragma unroll
        for (int kk = 0; kk < 2; ++kk)
            #pragma unroll
            for (int i = 0; i < 4; ++i)
                #pragma unroll
                for (int j = 0; j < 4; ++j)
                    acc[i][j] = mfma16(af[i][kk], bff[j][kk], acc[i][j]);
        __builtin_amdgcn_s_setprio(0);
    }

    if (MODE == 0) {
        #pragma unroll
        for (int j = 0; j < 4; ++j) {
            const int ncol = n0 + wc * 64 + j * 16 + l15;
            const int which = ncol >> 11;
            const int oo = ncol & 2047;
            const int head = oo >> 7;
            const int d = oo & 127;
            _Float16* dst = (which == 0) ? Qo : (which == 1) ? Ko : Vo;
            const float scl = (which == 0) ? 0.08838834764831845f : 1.0f;
            #pragma unroll
            for (int i = 0; i < 4; ++i) {
                #pragma unroll
                for (int r = 0; r < 4; ++r) {
                    const int m = m0 + wr * 64 + i * 16 + lq * 4 + r;
                    const int b = m >> 11, tt = m & 2047;
                    dst[((size_t)(b * NH + head) * TSEQ + tt) * HD + d] =
                        (_Float16)(acc[i][j][r] * scl);
                }
            }
        }
    } else {
        #pragma unroll
        for (int i = 0; i < 4; ++i)
            #pragma unroll
            for (int j = 0; j < 4; ++j)
                #pragma unroll
                for (int r = 0; r < 4; ++r) {
                    const int m = m0 + wr * 64 + i * 16 + lq * 4 + r;
                    const int n = n0 + wc * 64 + j * 16 + l15;
                    C[(size_t)m * HID + n] = acc[i][j][r];
                }
    }
}

// ---- GEMM small (R8/R9-proven on out-proj): 128^2, 256 thr, 2-ring + vmcnt(8) ----
template <int MODE>
__global__ __launch_bounds__(256, 2)
void gemm_small(const _Float16* __restrict__ A, const _Float16* __restrict__ B,
                float* __restrict__ C, int NB) {
    __shared__ __align__(16) _Float16 As[2][128 * 64];
    __shared__ __align__(16) _Float16 Bs[2][128 * 64];

    const int tid  = threadIdx.x;
    const int lane = tid & 63;
    const int w    = tid >> 6;
    const int l15  = lane & 15;
    const int lq   = lane >> 4;
    const int wr   = w >> 1, wc = w & 1;

    const int bid = (int)blockIdx.x;
    const int cpx = (int)gridDim.x >> 3;
    const int swz = (bid & 7) * cpx + (bid >> 3);
    const int bn  = swz % NB, bm = swz / NB;
    const int m0  = bm * 128, n0 = bn * 128;

    const _Float16* Ab = A + (size_t)m0 * GK;
    const _Float16* Bb = B + (size_t)n0 * GK;

    auto stage = [&](int t, int b) {
        const int k0 = t * 64;
        #pragma unroll
        for (int it = 0; it < 4; ++it) {
            const int slot = it * 256 + tid;
            const int row = slot >> 3, c16 = slot & 7;
            const int srcb = c16 ^ (row & 7);
            async_copy16(Ab + (size_t)row * GK + k0 + srcb * 8,
                         (char*)As[b] + slot * 16);
        }
        #pragma unroll
        for (int it = 0; it < 4; ++it) {
            const int slot = it * 256 + tid;
            const int row = slot >> 3, c16 = slot & 7;
            const int srcb = c16 ^ (row & 7);
            async_copy16(Bb + (size_t)row * GK + k0 + srcb * 8,
                         (char*)Bs[b] + slot * 16);
        }
    };

    f32x4 acc[4][4] = {};

    stage(0, 0);
    stage(1, 1);

    for (int t = 0; t < NKT; ++t) {
        const int cur = t & 1;
        if (t + 1 < NKT) asm volatile("s_waitcnt vmcnt(8)" ::: "memory");
        else             asm volatile("s_waitcnt vmcnt(0)" ::: "memory");
        __builtin_amdgcn_s_barrier();
        __builtin_amdgcn_sched_barrier(0);

        const char* At_ = (const char*)As[cur];
        const char* Bt_ = (const char*)Bs[cur];

        f16x8 af[4][2], bff[4][2];
        #pragma unroll
        for (int i = 0; i < 4; ++i)
            #pragma unroll
            for (int kk = 0; kk < 2; ++kk) {
                const int ra = wr * 64 + i * 16 + l15;
                af[i][kk]  = *(const f16x8*)(At_ + ra * 128 + (((kk * 4 + lq) ^ (ra & 7)) << 4));
                const int rb = wc * 64 + i * 16 + l15;
                bff[i][kk] = *(const f16x8*)(Bt_ + rb * 128 + (((kk * 4 + lq) ^ (rb & 7)) << 4));
            }
        asm volatile("s_waitcnt lgkmcnt(0)" ::: "memory");
        __builtin_amdgcn_sched_barrier(0);
        __builtin_amdgcn_s_barrier();
        __builtin_amdgcn_sched_barrier(0);

        if (t + 2 < NKT) stage(t + 2, cur);

        __builtin_amdgcn_s_setprio(1);
        #pragma unroll
        for (int kk = 0; kk < 2; ++kk)
            #pragma unroll
            for (int i = 0; i < 4; ++i)
                #pragma unroll
                for (int j = 0; j < 4; ++j)
                    acc[i][j] = mfma16(af[i][kk], bff[j][kk], acc[i][j]);
        __builtin_amdgcn_s_setprio(0);
    }

    #pragma unroll
    for (int i = 0; i < 4; ++i)
        #pragma unroll
        for (int j = 0; j < 4; ++j)
            #pragma unroll
            for (int r = 0; r < 4; ++r) {
                const int m = m0 + wr * 64 + i * 16 + lq * 4 + r;
                const int n = n0 + wc * 64 + j * 16 + l15;
                C[(size_t)m * HID + n] = acc[i][j][r];
            }
}

// ---- causal flash attention v7: swapped QK^T + in-register P ----
// S^T = mfma(K,Q): lane (l15,lq) holds P[kv=kv0+nf*16+lq*4+r][q=l15].
// Per-lane scalar softmax state (m_run, partial osum; cross-lq combine at end).
// P -> PV A-frag via cvt_pkrtz + shfl + target-side select (no P LDS).
// Single-buffered Ks/Vt (32KB LDS), 2 barriers/tile, register V-prefetch.
__global__ __launch_bounds__(256)
void attn_fwd(const _Float16* __restrict__ Q, const _Float16* __restrict__ K,
              const _Float16* __restrict__ V, _Float16* __restrict__ O) {
    __shared__ __align__(16) char Ks[64 * 256];   // [64][128] f16, swizzled (16KB)
    __shared__ __align__(16) char Vt[128 * 128];  // [128][64] f16 V^T, swizzled (16KB)

    const int tid  = threadIdx.x;
    const int lane = tid & 63;
    const int w    = tid >> 6;      // 0..3
    const int l15  = lane & 15;
    const int lq   = lane >> 4;
    const int lq1  = lq >> 1;                      // 0,0,1,1
    const int laneA = l15 + ((lane & 16) << 1);    // l15 + 32*(lq&1)
    const int laneB = laneA + 16;

    const int bh   = (int)blockIdx.x & 31;
    const int pair = (int)blockIdx.x >> 5;   // 0..15
    const int b = bh >> 4, h = bh & 15;

    const size_t base = (size_t)bh * TSEQ * HD;
    const _Float16* Qp = Q + base;
    const _Float16* Kp = K + base;
    const _Float16* Vp = V + base;

    uint4 vv[4];
    auto loadV = [&](int t) {
        const int row = tid & 63;
        #pragma unroll
        for (int it = 0; it < 4; ++it) {
            const int c8 = w * 4 + it;
            vv[it] = *(const uint4*)(Vp + (size_t)(t * 64 + row) * HD + c8 * 8);
        }
    };
    auto stageK = [&](int t) {
        #pragma unroll
        for (int it = 0; it < 4; ++it) {
            const int slot = it * 256 + tid;
            const int row = slot >> 4, c16 = slot & 15;
            const int srcb = c16 ^ (row & 7);
            async_copy16(Kp + (size_t)(t * 64 + row) * HD + srcb * 8, Ks + slot * 16);
        }
    };
    auto writeV = [&]() {
        const int row = tid & 63;
        #pragma unroll
        for (int it = 0; it < 4; ++it) {
            const int c8 = w * 4 + it;
            const uint32_t wrd[4] = {vv[it].x, vv[it].y, vv[it].z, vv[it].w};
            #pragma unroll
            for (int p2 = 0; p2 < 4; ++p2) {
                const int d0 = c8 * 8 + p2 * 2, d1 = d0 + 1;
                int b0 = d0 * 128 + row * 2; b0 ^= (d0 & 7) << 4;
                int b1 = d1 * 128 + row * 2; b1 ^= (d1 & 7) << 4;
                *(ushort_t*)(Vt + b0) = (ushort_t)(wrd[p2] & 0xffffu);
                *(ushort_t*)(Vt + b1) = (ushort_t)(wrd[p2] >> 16);
            }
        }
    };

    for (int phase = 0; phase < 2; ++phase) {
        const int qt = phase ? pair : (31 - pair);
        const int q0 = qt * 64;
        const int NT = qt + 1;

        if (phase) __syncthreads();

        const int qrow = q0 + w * 16 + l15;
        f16x8 qf[4];
        #pragma unroll
        for (int ks = 0; ks < 4; ++ks)
            qf[ks] = *(const f16x8*)(Qp + (size_t)qrow * HD + ks * 32 + lq * 8);

        f32x4 o[8] = {};
        float m_run = -1e30f;
        float osum  = 0.0f;          // per-lane partial (this lane's kv slice, q=l15)

        stageK(0);
        loadV(0);

        for (int t = 0; t < NT; ++t) {
            writeV();
            __syncthreads();
            if (t + 1 < NT) loadV(t + 1);

            const int kv0 = t * 64;
            // S^T = K Q^T : lane holds kv rows (nf*16+lq*4+r), q col = l15
            f32x4 s[4] = {};
            __builtin_amdgcn_s_setprio(1);
            #pragma unroll
            for (int ks = 0; ks < 4; ++ks) {
                #pragma unroll
                for (int nf = 0; nf < 4; ++nf) {
                    const int r   = nf * 16 + l15;
                    const int blk = (ks * 4 + lq) ^ (r & 7);
                    const f16x8 kf = *(const f16x8*)(Ks + r * 256 + blk * 16);
                    s[nf] = mfma16(kf, qf[ks], s[nf]);   // swapped operands
                }
            }
            __builtin_amdgcn_s_setprio(0);

            if (kv0 + 63 > q0 + w * 16) {   // diagonal-crossing for this wave
                const int q_lane = q0 + w * 16 + l15;
                #pragma unroll
                for (int nf = 0; nf < 4; ++nf) {
                    #pragma unroll
                    for (int r = 0; r < 4; ++r) {
                        const int kv = kv0 + nf * 16 + lq * 4 + r;
                        if (kv > q_lane) s[nf][r] = -1e30f;
                    }
                }
            }

            // lazy max (per-lane scalar, q = l15)
            float lmax = -1e30f;
            #pragma unroll
            for (int nf = 0; nf < 4; ++nf)
                lmax = fmaxf(lmax, fmaxf(fmaxf(s[nf][0], s[nf][1]),
                                         fmaxf(s[nf][2], s[nf][3])));
            if (__any(lmax > m_run + 5.0f)) {
                float v = lmax;
                v = fmaxf(v, __shfl_xor(v, 16));
                v = fmaxf(v, __shfl_xor(v, 32));      // all lq copies of q agree
                const float mn = fmaxf(m_run, v);
                const float alpha = __builtin_exp2f((m_run - mn) * LOG2E);
                m_run = mn;
                osum *= alpha;
                float aq[4];
                #pragma unroll
                for (int r = 0; r < 4; ++r)
                    aq[r] = __shfl(alpha, lq * 4 + r);  // alpha for q-row lq*4+r
                #pragma unroll
                for (int df = 0; df < 8; ++df)
                    #pragma unroll
                    for (int r = 0; r < 4; ++r)
                        o[df][r] *= aq[r];
            }

            // P = exp(S - m): pack to f16 pairs in-register
            uint32_t pk[4][2];
            float psum = 0.0f;
            #pragma unroll
            for (int nf = 0; nf < 4; ++nf) {
                #pragma unroll
                for (int hh = 0; hh < 2; ++hh) {
                    const float pa = __builtin_exp2f((s[nf][2 * hh]     - m_run) * LOG2E);
                    const float pb = __builtin_exp2f((s[nf][2 * hh + 1] - m_run) * LOG2E);
                    psum += pa + pb;
                    pk[nf][hh] = pkrtz(pa, pb);
                }
            }
            osum += psum;

            // exchange: build PV A-frags pf[ks2] (P[q=l15][kv=ks2*32+lq*8+j])
            f16x8 pf[2];
            #pragma unroll
            for (int ks2 = 0; ks2 < 2; ++ks2) {
                union { uint32_t u[4]; f16x8 v; } pu;
                const uint32_t a0n0 = (uint32_t)__shfl((int)pk[2 * ks2][0],     laneA);
                const uint32_t a0n1 = (uint32_t)__shfl((int)pk[2 * ks2 + 1][0], laneA);
                const uint32_t a1n0 = (uint32_t)__shfl((int)pk[2 * ks2][1],     laneA);
                const uint32_t a1n1 = (uint32_t)__shfl((int)pk[2 * ks2 + 1][1], laneA);
                const uint32_t b0n0 = (uint32_t)__shfl((int)pk[2 * ks2][0],     laneB);
                const uint32_t b0n1 = (uint32_t)__shfl((int)pk[2 * ks2 + 1][0], laneB);
                const uint32_t b1n0 = (uint32_t)__shfl((int)pk[2 * ks2][1],     laneB);
                const uint32_t b1n1 = (uint32_t)__shfl((int)pk[2 * ks2 + 1][1], laneB);
                pu.u[0] = lq1 ? a0n1 : a0n0;
                pu.u[1] = lq1 ? a1n1 : a1n0;
                pu.u[2] = lq1 ? b0n1 : b0n0;
                pu.u[3] = lq1 ? b1n1 : b1n0;
                pf[ks2] = pu.v;
            }

            // O += P @ V
            __builtin_amdgcn_s_setprio(1);
            #pragma unroll
            for (int ks2 = 0; ks2 < 2; ++ks2) {
                #pragma unroll
                for (int df = 0; df < 8; ++df) {
                    const int vr   = df * 16 + l15;
                    const int vblk = (ks2 * 4 + lq) ^ (vr & 7);
                    const f16x8 vf = *(const f16x8*)(Vt + vr * 128 + vblk * 16);
                    o[df] = mfma16(pf[ks2], vf, o[df]);
                }
            }
            __builtin_amdgcn_s_setprio(0);

            if (t + 1 < NT) {
                __syncthreads();
                stageK(t + 1);
            }
        }

        // combine partial sums across lq (all share the same m history)
        float tot = osum;
        tot += __shfl_xor(tot, 16);
        tot += __shfl_xor(tot, 32);
        const float rl = 1.0f / tot;           // valid at lane with q = l15
        float rlq[4];
        #pragma unroll
        for (int r = 0; r < 4; ++r)
            rlq[r] = __shfl(rl, lq * 4 + r);   // 1/sum for q-row lq*4+r

        #pragma unroll
        for (int df = 0; df < 8; ++df) {
            #pragma unroll
            for (int r = 0; r < 4; ++r) {
                const int qg = q0 + w * 16 + lq * 4 + r;
                const int dg = df * 16 + l15;
                O[((size_t)(b * TSEQ + qg)) * HID + h * HD + dg] =
                    (_Float16)(o[df][r] * rlq[r]);
            }
        }
    }
}

extern "C" void kernel_launch(void* const* d_in, const int* in_sizes, int n_in,
                              void* d_out, int out_size, void* d_ws, size_t ws_size,
                              hipStream_t stream) {
    (void)in_sizes; (void)n_in; (void)out_size; (void)ws_size;
    const float* hs   = (const float*)d_in[0];
    const float* wqkv = (const float*)d_in[1];
    const float* wout = (const float*)d_in[2];

    char* ws = (char*)d_ws;
    size_t off = 0;
    _Float16* hs_h   = (_Float16*)(ws + off); off += (size_t)BATCH * TSEQ * HID * 2;
    _Float16* wqkv_h = (_Float16*)(ws + off); off += (size_t)3 * HID * HID * 2;
    _Float16* wout_h = (_Float16*)(ws + off); off += (size_t)HID * HID * 2;
    _Float16* Qh     = (_Float16*)(ws + off); off += (size_t)BATCH * NH * TSEQ * HD * 2;
    _Float16* Kh     = (_Float16*)(ws + off); off += (size_t)BATCH * NH * TSEQ * HD * 2;
    _Float16* Vh     = (_Float16*)(ws + off); off += (size_t)BATCH * NH * TSEQ * HD * 2;
    _Float16* At     = (_Float16*)(ws + off); off += (size_t)BATCH * TSEQ * HID * 2;

    const int n4_hs   = BATCH * TSEQ * HID / 4;
    const int n4_wqkv = 3 * HID * HID / 4;
    const int n4_wout = HID * HID / 4;
    const int n4_all  = n4_hs + n4_wqkv + n4_wout;
    cast_all<<<dim3((n4_all + 255) / 256), dim3(256), 0, stream>>>(
        (const float4*)hs, (const float4*)wqkv, (const float4*)wout,
        (f16x4*)hs_h, (f16x4*)wqkv_h, (f16x4*)wout_h, n4_hs, n4_wqkv, n4_wout);

    // GEMM1: M=4096, N=6144: BM=256 -> grid 16x48 = 768 blocks
    gemm_big<0><<<dim3(768), dim3(512), 0, stream>>>(
        hs_h, wqkv_h, nullptr, Qh, Kh, Vh, 48);

    attn_fwd<<<dim3(512), dim3(256), 0, stream>>>(Qh, Kh, Vh, At);

    // GEMM2: M=4096, N=2048: 128^2 -> grid 32x16 = 512 blocks
    gemm_small<1><<<dim3(512), dim3(256), 0, stream>>>(
        At, wout_h, (float*)d_out, 16);
}